// Round 2
// baseline (23368.387 us; speedup 1.0000x reference)
//
#include <hip/hip_runtime.h>
#include <math.h>

#define B_ 8
#define L_ 2048
#define D_ 1024
#define ED_ 2048
#define N_ 64
#define R_ 64
#define K_ 4
#define NL_ 3
#define NC_ 2
#define BL_ (B_*L_)

// ---------------------------------------------------------------------------
// Generic fp32 GEMM: C[M,N] = A[M,K] * W[N,K]^T
// A row-major with row stride lda; W row-major (N,K); C row-major stride N.
// Tiles: BM=128, BN=64, BK=8. 128 threads, each computes 8x8.
// Requires: M%128==0, N%64==0, K%8==0 (true for all call sites here).
// ---------------------------------------------------------------------------
__global__ __launch_bounds__(128)
void gemm_nt(const float* __restrict__ A, int lda,
             const float* __restrict__ W,
             float* __restrict__ C, int M, int Nn, int Kd)
{
    __shared__ float As[8][128];
    __shared__ float Ws[8][64];
    const int tid = threadIdx.x;
    const int tx = tid & 7;       // col group 0..7 -> 8 cols each
    const int ty = tid >> 3;      // row group 0..15 -> 8 rows each
    const int by = blockIdx.y * 128;
    const int bx = blockIdx.x * 64;

    float acc[8][8];
#pragma unroll
    for (int i = 0; i < 8; i++)
#pragma unroll
        for (int j = 0; j < 8; j++) acc[i][j] = 0.f;

    const int wcol = tid & 63;
    const int wk0  = (tid >> 6) * 4;

    for (int kt = 0; kt < Kd; kt += 8) {
        const float* Ap = A + (size_t)(by + tid) * lda + kt;
        float4 a0 = *(const float4*)(Ap);
        float4 a1 = *(const float4*)(Ap + 4);
        const float* Wp = W + (size_t)(bx + wcol) * Kd + kt + wk0;
        float4 w0 = *(const float4*)(Wp);
        __syncthreads();
        As[0][tid] = a0.x; As[1][tid] = a0.y; As[2][tid] = a0.z; As[3][tid] = a0.w;
        As[4][tid] = a1.x; As[5][tid] = a1.y; As[6][tid] = a1.z; As[7][tid] = a1.w;
        Ws[wk0 + 0][wcol] = w0.x; Ws[wk0 + 1][wcol] = w0.y;
        Ws[wk0 + 2][wcol] = w0.z; Ws[wk0 + 3][wcol] = w0.w;
        __syncthreads();
#pragma unroll
        for (int k = 0; k < 8; k++) {
            float4 av0 = *(const float4*)&As[k][ty * 8];
            float4 av1 = *(const float4*)&As[k][ty * 8 + 4];
            float4 wv0 = *(const float4*)&Ws[k][tx * 8];
            float4 wv1 = *(const float4*)&Ws[k][tx * 8 + 4];
            float a[8] = {av0.x, av0.y, av0.z, av0.w, av1.x, av1.y, av1.z, av1.w};
            float w[8] = {wv0.x, wv0.y, wv0.z, wv0.w, wv1.x, wv1.y, wv1.z, wv1.w};
#pragma unroll
            for (int i = 0; i < 8; i++)
#pragma unroll
                for (int j = 0; j < 8; j++)
                    acc[i][j] = fmaf(a[i], w[j], acc[i][j]);
        }
    }
#pragma unroll
    for (int i = 0; i < 8; i++) {
        float* Cp = C + (size_t)(by + ty * 8 + i) * Nn + bx + tx * 8;
#pragma unroll
        for (int j = 0; j < 8; j++) Cp[j] = acc[i][j];
    }
}

// ---------------------------------------------------------------------------
// Depthwise causal conv (K=4) + bias + SiLU.
// Reads xp = xz[:, :, 0:ED] (row stride 4096), writes xps (G,L,ED) contiguous.
// idx decode relies on L*ED = 2^22, ED = 2^11.
// ---------------------------------------------------------------------------
__global__ __launch_bounds__(256)
void conv_silu(const float* __restrict__ xz, const float* __restrict__ cw,
               const float* __restrict__ cb, float* __restrict__ xps)
{
    int idx = blockIdx.x * 256 + threadIdx.x;  // G*L*ED threads
    int e = idx & (ED_ - 1);
    int l = (idx >> 11) & (L_ - 1);
    int b = idx >> 22;
    const float w0 = cw[e * 4 + 0], w1 = cw[e * 4 + 1];
    const float w2 = cw[e * 4 + 2], w3 = cw[e * 4 + 3];
    const float* base = xz + (size_t)(b * L_) * 4096 + e;
    float x0 = (l >= 3) ? base[(size_t)(l - 3) * 4096] : 0.f;
    float x1 = (l >= 2) ? base[(size_t)(l - 2) * 4096] : 0.f;
    float x2 = (l >= 1) ? base[(size_t)(l - 1) * 4096] : 0.f;
    float x3 = base[(size_t)l * 4096];
    float v = cb[e] + w0 * x0 + w1 * x1 + w2 * x2 + w3 * x3;
    v = v / (1.f + __expf(-v));    // SiLU
    xps[idx] = v;
}

// ---------------------------------------------------------------------------
// Selective scan, with the delta-GEMM (K=64) + softplus fused in.
// 16 threads per channel, 4 states per thread (n = 4*j + m).
// Block: 256 threads = 16 channels. Grid: G * ED/16 blocks (b = blk >> 7).
// Epilogue fused: y = (scan + xp*Dp) * silu(z), written into xz[:, :, 0:ED].
// ---------------------------------------------------------------------------
__global__ __launch_bounds__(256)
void scan_kernel(const float* __restrict__ xdbl, const float* __restrict__ xps,
                 const float* __restrict__ xz,   const float* __restrict__ A_log,
                 const float* __restrict__ Wdt,  const float* __restrict__ bdt,
                 const float* __restrict__ Dp,   float* __restrict__ y)
{
    const int tid = threadIdx.x;
    const int c = tid >> 4;           // channel within block 0..15
    const int j = tid & 15;           // state group 0..15
    const int b = blockIdx.x >> 7;
    const int e = ((blockIdx.x & 127) << 4) + c;

    float4 Al = *(const float4*)(A_log + (size_t)e * 64 + 4 * j);
    const float A0 = -__expf(Al.x), A1 = -__expf(Al.y);
    const float A2 = -__expf(Al.z), A3 = -__expf(Al.w);
    float4 Wd = *(const float4*)(Wdt + (size_t)e * 64 + 4 * j);
    const float bde = bdt[e];
    const float dpe = Dp[e];

    float h0 = 0.f, h1 = 0.f, h2 = 0.f, h3 = 0.f;
    size_t rowED   = (size_t)(b * L_) * ED_ + e;
    size_t row192  = (size_t)(b * L_) * 192;
    size_t row4096 = (size_t)(b * L_) * 4096;

    // prefetch step 0
    float4 dtv = *(const float4*)(xdbl + row192 + 4 * j);
    float4 Bv  = *(const float4*)(xdbl + row192 + 64 + 4 * j);
    float4 Cv  = *(const float4*)(xdbl + row192 + 128 + 4 * j);
    float  xv  = xps[rowED];

    for (int l = 0; l < L_; ++l) {
        // prefetch next step
        float4 dtn, Bn, Cn; float xn;
        if (l + 1 < L_) {
            size_t r192n = row192 + 192;
            dtn = *(const float4*)(xdbl + r192n + 4 * j);
            Bn  = *(const float4*)(xdbl + r192n + 64 + 4 * j);
            Cn  = *(const float4*)(xdbl + r192n + 128 + 4 * j);
            xn  = xps[rowED + ED_];
        } else { dtn = make_float4(0,0,0,0); Bn = dtn; Cn = dtn; xn = 0.f; }

        // delta = softplus(dt . Wdt[e] + b_dt[e])  (fused K=64 dot, 16-lane reduce)
        float pd = dtv.x * Wd.x + dtv.y * Wd.y + dtv.z * Wd.z + dtv.w * Wd.w;
        pd += __shfl_xor(pd, 1); pd += __shfl_xor(pd, 2);
        pd += __shfl_xor(pd, 4); pd += __shfl_xor(pd, 8);
        pd += bde;
        float d = (pd > 20.f) ? pd : log1pf(__expf(pd));

        float dx = d * xv;
        h0 = __expf(d * A0) * h0 + dx * Bv.x;
        h1 = __expf(d * A1) * h1 + dx * Bv.y;
        h2 = __expf(d * A2) * h2 + dx * Bv.z;
        h3 = __expf(d * A3) * h3 + dx * Bv.w;

        float acc = h0 * Cv.x + h1 * Cv.y + h2 * Cv.z + h3 * Cv.w;
        acc += __shfl_xor(acc, 1); acc += __shfl_xor(acc, 2);
        acc += __shfl_xor(acc, 4); acc += __shfl_xor(acc, 8);

        if (j == 0) {
            float z = xz[row4096 + ED_ + e];
            float sz = z / (1.f + __expf(-z));
            y[row4096 + e] = (acc + xv * dpe) * sz;
        }
        dtv = dtn; Bv = Bn; Cv = Cn; xv = xn;
        rowED += ED_; row192 += 192; row4096 += 4096;
    }
}

// ---------------------------------------------------------------------------
// x = rmsnorm(t, norm_w) + x   (one block per (b,l) row, D=1024)
// ---------------------------------------------------------------------------
__global__ __launch_bounds__(256)
void rmsnorm_res(const float* __restrict__ t, const float* __restrict__ nw,
                 float* __restrict__ x)
{
    const int row = blockIdx.x;
    const int tid = threadIdx.x;
    const float* tr = t + (size_t)row * D_;
    float* xr = x + (size_t)row * D_;
    float4 v = *(const float4*)(tr + tid * 4);
    float ss = v.x * v.x + v.y * v.y + v.z * v.z + v.w * v.w;
#pragma unroll
    for (int m = 1; m < 64; m <<= 1) ss += __shfl_xor(ss, m);
    __shared__ float red[4];
    if ((tid & 63) == 0) red[tid >> 6] = ss;
    __syncthreads();
    float tot = red[0] + red[1] + red[2] + red[3];
    float scale = rsqrtf(tot * (1.f / (float)D_) + 1e-5f);
    float4 w = *(const float4*)(nw + tid * 4);
    float4 xo = *(const float4*)(xr + tid * 4);
    xo.x += v.x * scale * w.x;
    xo.y += v.y * scale * w.y;
    xo.z += v.z * scale * w.z;
    xo.w += v.w * scale * w.w;
    *(float4*)(xr + tid * 4) = xo;
}

// ---------------------------------------------------------------------------
// Head: out[b,c] = x[b, L-1, :] . W_head[c, :] + b_head[c]
// Grid: G*NC blocks; out pre-offset by caller for the batch group.
// ---------------------------------------------------------------------------
__global__ __launch_bounds__(256)
void head_kernel(const float* __restrict__ x, const float* __restrict__ Wh,
                 const float* __restrict__ bh, float* __restrict__ out)
{
    const int b = blockIdx.x >> 1, c = blockIdx.x & 1;
    const int tid = threadIdx.x;
    const float* xr = x + (size_t)(b * L_ + (L_ - 1)) * D_;
    const float* wr = Wh + c * D_;
    float4 xv = *(const float4*)(xr + tid * 4);
    float4 wv = *(const float4*)(wr + tid * 4);
    float s = xv.x * wv.x + xv.y * wv.y + xv.z * wv.z + xv.w * wv.w;
#pragma unroll
    for (int m = 1; m < 64; m <<= 1) s += __shfl_xor(s, m);
    __shared__ float red[4];
    if ((tid & 63) == 0) red[tid >> 6] = s;
    __syncthreads();
    if (tid == 0) out[b * 2 + c] = red[0] + red[1] + red[2] + red[3] + bh[c];
}

// ---------------------------------------------------------------------------
extern "C" void kernel_launch(void* const* d_in, const int* in_sizes, int n_in,
                              void* d_out, int out_size, void* d_ws, size_t ws_size,
                              hipStream_t stream)
{
    const float* x_in   = (const float*)d_in[0];
    const float* W_in   = (const float*)d_in[1];
    const float* conv_w = (const float*)d_in[2];
    const float* conv_b = (const float*)d_in[3];
    const float* W_x    = (const float*)d_in[4];
    const float* W_dt   = (const float*)d_in[5];
    const float* b_dt   = (const float*)d_in[6];
    const float* A_log  = (const float*)d_in[7];
    const float* D_p    = (const float*)d_in[8];
    const float* W_out  = (const float*)d_in[9];
    const float* norm_w = (const float*)d_in[10];
    const float* W_head = (const float*)d_in[11];
    const float* b_head = (const float*)d_in[12];
    float* out = (float*)d_out;
    float* ws  = (float*)d_ws;

    // Batches are independent end-to-end; process groups of G batches so the
    // workspace footprint G * L*(D + 4096 + ED + 192) * 4B fits ws_size.
    // G=8 -> 460MB, 4 -> 230MB, 2 -> 115MB, 1 -> 58MB. ws_size is constant
    // across calls, so G is too (graph-capture safe).
    const size_t perB = (size_t)L_ * (D_ + 4096 + ED_ + 192) * sizeof(float);
    int G = 8;
    while (G > 1 && (size_t)G * perB > ws_size) G >>= 1;
    const int M = G * L_;   // rows per group

    // group-local workspace layout (floats):
    float* x_cur = ws;                             // M*D
    float* xz    = x_cur + (size_t)M * D_;         // M*4096 (xp | z)
    float* xps   = xz    + (size_t)M * 4096;       // M*ED
    float* xdbl  = xps   + (size_t)M * ED_;        // M*192
    float* ybuf  = xz;    // scan writes y into xz[:, :, 0:ED] (stride 4096)
    float* out_t = xps;   // GEMM3 output reuses xps after scan consumed it

    for (int g0 = 0; g0 < B_; g0 += G) {
        hipMemcpyAsync(x_cur, x_in + (size_t)g0 * L_ * D_,
                       (size_t)M * D_ * sizeof(float),
                       hipMemcpyDeviceToDevice, stream);

        for (int i = 0; i < NL_; ++i) {
            // 1) xz = x @ W_in^T   (M x 4096 x 1024)
            dim3 g1(2 * ED_ / 64, M / 128);
            gemm_nt<<<g1, 128, 0, stream>>>(x_cur, D_,
                                            W_in + (size_t)i * 2 * ED_ * D_,
                                            xz, M, 2 * ED_, D_);
            // 2) xps = silu(causal_conv(xp) + cb)
            conv_silu<<<(M * ED_) / 256, 256, 0, stream>>>(
                xz, conv_w + (size_t)i * ED_ * K_, conv_b + (size_t)i * ED_, xps);
            // 3) xdbl = xps @ W_x^T   (M x 192 x 2048)
            dim3 g2(192 / 64, M / 128);
            gemm_nt<<<g2, 128, 0, stream>>>(xps, ED_,
                                            W_x + (size_t)i * 192 * ED_,
                                            xdbl, M, 192, ED_);
            // 4) scan (delta GEMM fused) -> y into xz first half
            scan_kernel<<<G * (ED_ / 16), 256, 0, stream>>>(
                xdbl, xps, xz,
                A_log + (size_t)i * ED_ * N_,
                W_dt + (size_t)i * ED_ * R_,
                b_dt + (size_t)i * ED_,
                D_p + (size_t)i * ED_, ybuf);
            // 5) out_t = y @ W_out^T   (M x 1024 x 2048)
            dim3 g3(D_ / 64, M / 128);
            gemm_nt<<<g3, 128, 0, stream>>>(ybuf, 2 * ED_,
                                            W_out + (size_t)i * D_ * ED_,
                                            out_t, M, D_, ED_);
            // 6) x = rmsnorm(out_t) + x
            rmsnorm_res<<<M, 256, 0, stream>>>(out_t, norm_w + (size_t)i * D_,
                                               x_cur);
        }
        head_kernel<<<G * NC_, 256, 0, stream>>>(x_cur, W_head, b_head,
                                                 out + (size_t)g0 * NC_);
    }
}

// Round 3
// 10473.100 us; speedup vs baseline: 2.2313x; 2.2313x over previous
//
#include <hip/hip_runtime.h>
#include <math.h>

#define B_ 8
#define L_ 2048
#define D_ 1024
#define ED_ 2048
#define NL_ 3
#define NC_ 2

typedef unsigned short u16;
typedef unsigned int u32;
typedef __attribute__((ext_vector_type(8))) short short8;
typedef __attribute__((ext_vector_type(4))) float f32x4;

__device__ __forceinline__ u16 f2b(float f) {
    u32 u = __float_as_uint(f);
    u = (u + 0x7FFFu + ((u >> 16) & 1u)) >> 16;
    return (u16)u;
}
__device__ __forceinline__ float b2f(u16 h) {
    return __uint_as_float(((u32)h) << 16);
}
__device__ __forceinline__ void cp16(const void* g, void* l) {
    __builtin_amdgcn_global_load_lds((const __attribute__((address_space(1))) u32*)g,
                                     (__attribute__((address_space(3))) u32*)l,
                                     16, 0, 0);
}

// ---------------------------------------------------------------------------
// fp32 -> bf16 cast (RNE)
// ---------------------------------------------------------------------------
__global__ __launch_bounds__(256)
void cast_bf16(const float* __restrict__ in, u16* __restrict__ out, int n)
{
    int i = blockIdx.x * 256 + threadIdx.x;
    if (i < n) out[i] = f2b(in[i]);
}

// ---------------------------------------------------------------------------
// bf16 MFMA GEMM: C[M,N] = A[M,K] * W[N,K]^T   (A, W bf16; C fp32 or bf16)
// BM=128, BN in {128,64}, BK=32. 256 threads = 4 waves.
// BN=128: waves 2x2, each 64x64 (MI=NI=4). BN=64: waves 4x1, each 32x64.
// Staging via global_load_lds width 16 (wave-uniform LDS base + lane*16).
// mfma_f32_16x16x32_bf16: A frag A[m=lane&15][k=(lane>>4)*8+j];
// C/D: col=lane&15, row=(lane>>4)*4+reg.
// ---------------------------------------------------------------------------
template<int BN, bool OUT_BF16>
__global__ __launch_bounds__(256)
void gemm_mfma(const u16* __restrict__ A, int lda,
               const u16* __restrict__ W,
               void* __restrict__ Cout, int ldc, int Kd)
{
    constexpr int WX = (BN == 128) ? 2 : 1;   // waves along N
    constexpr int WY = 4 / WX;                // waves along M
    constexpr int MI = (128 / WY) / 16;       // 4 or 2
    constexpr int NI = (BN / WX) / 16;        // 4
    constexpr int BISS = BN * 64 / 4096;      // B staging issues: 2 or 1

    __shared__ u16 As[128 * 32];
    __shared__ u16 Bs[BN * 32];

    const int tid  = threadIdx.x;
    const int wave = tid >> 6;
    const int lane = tid & 63;
    const int wy = wave / WX, wx = wave % WX;
    const int by = blockIdx.y * 128;
    const int bx = blockIdx.x * BN;
    const int lr = lane & 15;
    const int lk = (lane >> 4) * 8;

    f32x4 acc[MI][NI];
#pragma unroll
    for (int i = 0; i < MI; i++)
#pragma unroll
        for (int j = 0; j < NI; j++) acc[i][j] = (f32x4){0.f, 0.f, 0.f, 0.f};

    // staging: chunk c = q*256 + tid; row = c>>2, col8 = c&3 (256%4==0)
    const u16* Ag0 = A + (size_t)(by + (tid >> 2)) * lda + (tid & 3) * 8;
    const u16* Bg0 = W + (size_t)(bx + (tid >> 2)) * Kd + (tid & 3) * 8;
    u16* ldsA0 = &As[wave * 512];
    u16* ldsA1 = &As[2048 + wave * 512];
    u16* ldsB0 = &Bs[wave * 512];
    u16* ldsB1 = &Bs[2048 + wave * 512];   // only used when BISS==2

    for (int kt = 0; kt < Kd; kt += 32) {
        __syncthreads();   // all waves done reading previous tile
        cp16(Ag0 + kt, ldsA0);
        cp16(Ag0 + (size_t)64 * lda + kt, ldsA1);
        cp16(Bg0 + kt, ldsB0);
        if (BISS == 2) cp16(Bg0 + (size_t)64 * Kd + kt, ldsB1);
        __syncthreads();   // vmcnt(0) drain + barrier -> LDS populated

        short8 af[MI], bf[NI];
#pragma unroll
        for (int mi = 0; mi < MI; mi++) {
            int m = wy * (MI * 16) + mi * 16 + lr;
            af[mi] = *(const short8*)&As[m * 32 + lk];
        }
#pragma unroll
        for (int ni = 0; ni < NI; ni++) {
            int n = wx * (NI * 16) + ni * 16 + lr;
            bf[ni] = *(const short8*)&Bs[n * 32 + lk];
        }
#pragma unroll
        for (int mi = 0; mi < MI; mi++)
#pragma unroll
            for (int ni = 0; ni < NI; ni++)
                acc[mi][ni] = __builtin_amdgcn_mfma_f32_16x16x32_bf16(
                    af[mi], bf[ni], acc[mi][ni], 0, 0, 0);
    }

#pragma unroll
    for (int mi = 0; mi < MI; mi++) {
#pragma unroll
        for (int ni = 0; ni < NI; ni++) {
            int col = bx + wx * (NI * 16) + ni * 16 + lr;
#pragma unroll
            for (int r = 0; r < 4; r++) {
                int row = by + wy * (MI * 16) + mi * 16 + (lane >> 4) * 4 + r;
                if (OUT_BF16)
                    ((u16*)Cout)[(size_t)row * ldc + col] = f2b(acc[mi][ni][r]);
                else
                    ((float*)Cout)[(size_t)row * ldc + col] = acc[mi][ni][r];
            }
        }
    }
}

// ---------------------------------------------------------------------------
// fp32 GEMM + bias + softplus: delta = softplus(A @ W^T + bias)
// BM=128, BN=64, BK=8, 128 threads, 8x8 each. (small K=64 GEMM)
// ---------------------------------------------------------------------------
__global__ __launch_bounds__(128)
void gemm_delta(const float* __restrict__ A, int lda,
                const float* __restrict__ W, const float* __restrict__ bias,
                float* __restrict__ C, int Nn, int Kd)
{
    __shared__ float As[8][128];
    __shared__ float Ws[8][64];
    const int tid = threadIdx.x;
    const int tx = tid & 7;
    const int ty = tid >> 3;
    const int by = blockIdx.y * 128;
    const int bx = blockIdx.x * 64;

    float acc[8][8];
#pragma unroll
    for (int i = 0; i < 8; i++)
#pragma unroll
        for (int j = 0; j < 8; j++) acc[i][j] = 0.f;

    const int wcol = tid & 63;
    const int wk0  = (tid >> 6) * 4;

    for (int kt = 0; kt < Kd; kt += 8) {
        const float* Ap = A + (size_t)(by + tid) * lda + kt;
        float4 a0 = *(const float4*)(Ap);
        float4 a1 = *(const float4*)(Ap + 4);
        const float* Wp = W + (size_t)(bx + wcol) * Kd + kt + wk0;
        float4 w0 = *(const float4*)(Wp);
        __syncthreads();
        As[0][tid] = a0.x; As[1][tid] = a0.y; As[2][tid] = a0.z; As[3][tid] = a0.w;
        As[4][tid] = a1.x; As[5][tid] = a1.y; As[6][tid] = a1.z; As[7][tid] = a1.w;
        Ws[wk0 + 0][wcol] = w0.x; Ws[wk0 + 1][wcol] = w0.y;
        Ws[wk0 + 2][wcol] = w0.z; Ws[wk0 + 3][wcol] = w0.w;
        __syncthreads();
#pragma unroll
        for (int k = 0; k < 8; k++) {
            float4 av0 = *(const float4*)&As[k][ty * 8];
            float4 av1 = *(const float4*)&As[k][ty * 8 + 4];
            float4 wv0 = *(const float4*)&Ws[k][tx * 8];
            float4 wv1 = *(const float4*)&Ws[k][tx * 8 + 4];
            float a[8] = {av0.x, av0.y, av0.z, av0.w, av1.x, av1.y, av1.z, av1.w};
            float w[8] = {wv0.x, wv0.y, wv0.z, wv0.w, wv1.x, wv1.y, wv1.z, wv1.w};
#pragma unroll
            for (int i = 0; i < 8; i++)
#pragma unroll
                for (int j = 0; j < 8; j++)
                    acc[i][j] = fmaf(a[i], w[j], acc[i][j]);
        }
    }
#pragma unroll
    for (int i = 0; i < 8; i++) {
        float* Cp = C + (size_t)(by + ty * 8 + i) * Nn + bx + tx * 8;
#pragma unroll
        for (int j = 0; j < 8; j++) {
            float v = acc[i][j] + bias[bx + tx * 8 + j];
            Cp[j] = (v > 20.f) ? v : log1pf(__expf(v));
        }
    }
}

// ---------------------------------------------------------------------------
// Depthwise causal conv (K=4) + bias + SiLU. bf16 in (xz, stride 4096), bf16 out.
// ---------------------------------------------------------------------------
__global__ __launch_bounds__(256)
void conv_silu(const u16* __restrict__ xzb, const float* __restrict__ cw,
               const float* __restrict__ cb, u16* __restrict__ xpb)
{
    int idx = blockIdx.x * 256 + threadIdx.x;  // G*L*ED threads
    int e = idx & (ED_ - 1);
    int l = (idx >> 11) & (L_ - 1);
    int b = idx >> 22;
    const float w0 = cw[e * 4 + 0], w1 = cw[e * 4 + 1];
    const float w2 = cw[e * 4 + 2], w3 = cw[e * 4 + 3];
    const u16* base = xzb + (size_t)(b * L_) * 4096 + e;
    float x0 = (l >= 3) ? b2f(base[(size_t)(l - 3) * 4096]) : 0.f;
    float x1 = (l >= 2) ? b2f(base[(size_t)(l - 2) * 4096]) : 0.f;
    float x2 = (l >= 1) ? b2f(base[(size_t)(l - 1) * 4096]) : 0.f;
    float x3 = b2f(base[(size_t)l * 4096]);
    float v = cb[e] + w0 * x0 + w1 * x1 + w2 * x2 + w3 * x3;
    v = v / (1.f + __expf(-v));
    xpb[idx] = f2b(v);
}

// ---------------------------------------------------------------------------
// Selective scan (delta precomputed). 16 lanes/channel, 4 states/lane.
// Block 256 = 16 channels; grid G*128. y written bf16 IN PLACE over xpb
// (safe: the 16 lanes of a channel are in one wave; row-l write is after
// the row-(l+1) prefetch in lockstep).
// ---------------------------------------------------------------------------
__global__ __launch_bounds__(256)
void scan_kernel(const float* __restrict__ delta, const float* __restrict__ xdbl,
                 const u16* __restrict__ xzb, u16* __restrict__ xpb,
                 const float* __restrict__ A_log, const float* __restrict__ Dp)
{
    const int tid = threadIdx.x;
    const int c = tid >> 4;
    const int j = tid & 15;
    const int b = blockIdx.x >> 7;
    const int e = ((blockIdx.x & 127) << 4) + c;

    float4 Al = *(const float4*)(A_log + (size_t)e * 64 + 4 * j);
    const float A0 = -__expf(Al.x), A1 = -__expf(Al.y);
    const float A2 = -__expf(Al.z), A3 = -__expf(Al.w);
    const float dpe = Dp[e];

    float h0 = 0.f, h1 = 0.f, h2 = 0.f, h3 = 0.f;
    size_t rowED  = (size_t)(b * L_) * ED_ + e;   // delta / x / y index
    size_t row192 = (size_t)(b * L_) * 192;
    size_t rowZ   = (size_t)(b * L_) * 4096 + ED_ + e;

    float  dv = delta[rowED];
    float4 Bv = *(const float4*)(xdbl + row192 + 64 + 4 * j);
    float4 Cv = *(const float4*)(xdbl + row192 + 128 + 4 * j);
    float  xv = b2f(xpb[rowED]);

    for (int l = 0; l < L_; ++l) {
        float dn = 0.f, xn = 0.f; float4 Bn, Cn;
        if (l + 1 < L_) {
            dn = delta[rowED + ED_];
            Bn = *(const float4*)(xdbl + row192 + 192 + 64 + 4 * j);
            Cn = *(const float4*)(xdbl + row192 + 192 + 128 + 4 * j);
            xn = b2f(xpb[rowED + ED_]);
        } else { Bn = make_float4(0,0,0,0); Cn = Bn; }

        float dx = dv * xv;
        h0 = __expf(dv * A0) * h0 + dx * Bv.x;
        h1 = __expf(dv * A1) * h1 + dx * Bv.y;
        h2 = __expf(dv * A2) * h2 + dx * Bv.z;
        h3 = __expf(dv * A3) * h3 + dx * Bv.w;

        float acc = h0 * Cv.x + h1 * Cv.y + h2 * Cv.z + h3 * Cv.w;
        acc += __shfl_xor(acc, 1); acc += __shfl_xor(acc, 2);
        acc += __shfl_xor(acc, 4); acc += __shfl_xor(acc, 8);

        if (j == 0) {
            float z = b2f(xzb[rowZ]);
            float sz = z / (1.f + __expf(-z));
            xpb[rowED] = f2b((acc + xv * dpe) * sz);
        }
        dv = dn; Bv = Bn; Cv = Cn; xv = xn;
        rowED += ED_; row192 += 192; rowZ += 4096;
    }
}

// ---------------------------------------------------------------------------
// x = rmsnorm(t, norm_w) + x ; also writes bf16 copy of new x.
// ---------------------------------------------------------------------------
__global__ __launch_bounds__(256)
void rmsnorm_res(const float* __restrict__ t, const float* __restrict__ nw,
                 float* __restrict__ x, u16* __restrict__ xb)
{
    const int row = blockIdx.x;
    const int tid = threadIdx.x;
    const float* tr = t + (size_t)row * D_;
    float* xr = x + (size_t)row * D_;
    u16* xbr = xb + (size_t)row * D_;
    float4 v = *(const float4*)(tr + tid * 4);
    float ss = v.x * v.x + v.y * v.y + v.z * v.z + v.w * v.w;
#pragma unroll
    for (int m = 1; m < 64; m <<= 1) ss += __shfl_xor(ss, m);
    __shared__ float red[4];
    if ((tid & 63) == 0) red[tid >> 6] = ss;
    __syncthreads();
    float tot = red[0] + red[1] + red[2] + red[3];
    float scale = rsqrtf(tot * (1.f / (float)D_) + 1e-5f);
    float4 w = *(const float4*)(nw + tid * 4);
    float4 xo = *(const float4*)(xr + tid * 4);
    xo.x += v.x * scale * w.x;
    xo.y += v.y * scale * w.y;
    xo.z += v.z * scale * w.z;
    xo.w += v.w * scale * w.w;
    *(float4*)(xr + tid * 4) = xo;
    ushort4 hb;
    hb.x = f2b(xo.x); hb.y = f2b(xo.y); hb.z = f2b(xo.z); hb.w = f2b(xo.w);
    *(ushort4*)(xbr + tid * 4) = hb;
}

// ---------------------------------------------------------------------------
__global__ __launch_bounds__(256)
void head_kernel(const float* __restrict__ x, const float* __restrict__ Wh,
                 const float* __restrict__ bh, float* __restrict__ out)
{
    const int b = blockIdx.x >> 1, c = blockIdx.x & 1;
    const int tid = threadIdx.x;
    const float* xr = x + (size_t)(b * L_ + (L_ - 1)) * D_;
    const float* wr = Wh + c * D_;
    float4 xv = *(const float4*)(xr + tid * 4);
    float4 wv = *(const float4*)(wr + tid * 4);
    float s = xv.x * wv.x + xv.y * wv.y + xv.z * wv.z + xv.w * wv.w;
#pragma unroll
    for (int m = 1; m < 64; m <<= 1) s += __shfl_xor(s, m);
    __shared__ float red[4];
    if ((tid & 63) == 0) red[tid >> 6] = s;
    __syncthreads();
    if (tid == 0) out[b * 2 + c] = red[0] + red[1] + red[2] + red[3] + bh[c];
}

// ---------------------------------------------------------------------------
extern "C" void kernel_launch(void* const* d_in, const int* in_sizes, int n_in,
                              void* d_out, int out_size, void* d_ws, size_t ws_size,
                              hipStream_t stream)
{
    const float* x_in   = (const float*)d_in[0];
    const float* W_in   = (const float*)d_in[1];
    const float* conv_w = (const float*)d_in[2];
    const float* conv_b = (const float*)d_in[3];
    const float* W_x    = (const float*)d_in[4];
    const float* W_dt   = (const float*)d_in[5];
    const float* b_dt   = (const float*)d_in[6];
    const float* A_log  = (const float*)d_in[7];
    const float* D_p    = (const float*)d_in[8];
    const float* W_out  = (const float*)d_in[9];
    const float* norm_w = (const float*)d_in[10];
    const float* W_head = (const float*)d_in[11];
    const float* b_head = (const float*)d_in[12];
    float* out = (float*)d_out;

    // -------- bf16 weight region (fixed, head of ws) --------
    const size_t nWi = (size_t)NL_ * 2 * ED_ * D_;   // 12.58M
    const size_t nWx = (size_t)NL_ * 192 * ED_;      // 1.18M
    const size_t nWo = (size_t)NL_ * D_ * ED_;       // 6.29M
    u16* Wi_b = (u16*)d_ws;
    u16* Wx_b = Wi_b + nWi;
    u16* Wo_b = Wx_b + nWx;
    size_t wbytes = ((nWi + nWx + nWo) * 2 + 255) & ~(size_t)255;
    char* gb = (char*)d_ws + wbytes;
    size_t usable = ws_size - wbytes;

    cast_bf16<<<(int)(nWi / 256), 256, 0, stream>>>(W_in, Wi_b, (int)nWi);
    cast_bf16<<<(int)(nWx / 256), 256, 0, stream>>>(W_x,  Wx_b, (int)nWx);
    cast_bf16<<<(int)(nWo / 256), 256, 0, stream>>>(W_out, Wo_b, (int)nWo);

    // -------- group footprint: per batch 25344 B/row * 2048 rows = 49.5 MB --------
    const size_t perB = (size_t)L_ * (D_ * 4 + 192 * 4 + ED_ * 4 + 4096 * 2 + ED_ * 2);
    int G = 8;
    while (G > 1 && (size_t)G * perB > usable) G >>= 1;
    const int M = G * L_;

    // group-local layout
    float* x_cur = (float*)gb;                       // M*1024 f32
    float* xdbl  = x_cur + (size_t)M * D_;           // M*192  f32
    float* delta = xdbl + (size_t)M * 192;           // M*2048 f32
    u16*   x_b   = (u16*)delta;                      // alias (head of delta)
    u16*   xz_b  = (u16*)(delta + (size_t)M * ED_);  // M*4096 bf16
    u16*   xps_b = xz_b + (size_t)M * 4096;          // M*2048 bf16 (x, then y in place)
    float* out_t = (float*)xz_b;                     // alias (GEMM3 out, M*1024 f32)

    for (int g0 = 0; g0 < B_; g0 += G) {
        const float* xg = x_in + (size_t)g0 * L_ * D_;
        hipMemcpyAsync(x_cur, xg, (size_t)M * D_ * sizeof(float),
                       hipMemcpyDeviceToDevice, stream);
        cast_bf16<<<(M * D_) / 256, 256, 0, stream>>>(xg, x_b, M * D_);

        for (int i = 0; i < NL_; ++i) {
            // 1) xz = x @ W_in^T  (M x 4096 x 1024), bf16 out
            gemm_mfma<128, true><<<dim3(4096 / 128, M / 128), 256, 0, stream>>>(
                x_b, D_, Wi_b + (size_t)i * 2 * ED_ * D_, xz_b, 4096, D_);
            // 2) xps = silu(conv(xp) + cb), bf16
            conv_silu<<<(M * ED_) / 256, 256, 0, stream>>>(
                xz_b, conv_w + (size_t)i * ED_ * 4, conv_b + (size_t)i * ED_, xps_b);
            // 3) xdbl = xps @ W_x^T  (M x 192 x 2048), fp32 out
            gemm_mfma<64, false><<<dim3(192 / 64, M / 128), 256, 0, stream>>>(
                xps_b, ED_, Wx_b + (size_t)i * 192 * ED_, xdbl, 192, ED_);
            // 4) delta = softplus(dt @ W_dt^T + b_dt)  (M x 2048 x 64), fp32
            gemm_delta<<<dim3(ED_ / 64, M / 128), 128, 0, stream>>>(
                xdbl, 192, W_dt + (size_t)i * ED_ * 64, b_dt + (size_t)i * ED_,
                delta, ED_, 64);
            // 5) scan -> y (bf16, in place over xps_b)
            scan_kernel<<<G * 128, 256, 0, stream>>>(
                delta, xdbl, xz_b, xps_b,
                A_log + (size_t)i * ED_ * 64, D_p + (size_t)i * ED_);
            // 6) out_t = y @ W_out^T  (M x 1024 x 2048), fp32 out
            gemm_mfma<128, false><<<dim3(D_ / 128, M / 128), 256, 0, stream>>>(
                xps_b, ED_, Wo_b + (size_t)i * D_ * ED_, out_t, D_, ED_);
            // 7) x = rmsnorm(out_t) + x  (+ bf16 copy)
            rmsnorm_res<<<M, 256, 0, stream>>>(out_t, norm_w + (size_t)i * D_,
                                               x_cur, x_b);
        }
        head_kernel<<<G * NC_, 256, 0, stream>>>(x_cur, W_head, b_head,
                                                 out + (size_t)g0 * NC_);
    }
}

// Round 4
// 7449.413 us; speedup vs baseline: 3.1369x; 1.4059x over previous
//
#include <hip/hip_runtime.h>
#include <math.h>

#define B_ 8
#define L_ 2048
#define D_ 1024
#define ED_ 2048
#define NL_ 3
#define NC_ 2
#define SCH_ 128              // scan chunk length
#define NCH_ (L_ / SCH_)      // 16 chunks

typedef unsigned short u16;
typedef unsigned int u32;
typedef __attribute__((ext_vector_type(8))) short short8;
typedef __attribute__((ext_vector_type(4))) float f32x4;

__device__ __forceinline__ u16 f2b(float f) {
    u32 u = __float_as_uint(f);
    u = (u + 0x7FFFu + ((u >> 16) & 1u)) >> 16;
    return (u16)u;
}
__device__ __forceinline__ float b2f(u16 h) {
    return __uint_as_float(((u32)h) << 16);
}
__device__ __forceinline__ void cp16(const void* g, void* l) {
    __builtin_amdgcn_global_load_lds((const __attribute__((address_space(1))) u32*)g,
                                     (__attribute__((address_space(3))) u32*)l,
                                     16, 0, 0);
}

// ---------------------------------------------------------------------------
// fp32 -> bf16 cast (RNE)
// ---------------------------------------------------------------------------
__global__ __launch_bounds__(256)
void cast_bf16(const float* __restrict__ in, u16* __restrict__ out, int n)
{
    int i = blockIdx.x * 256 + threadIdx.x;
    if (i < n) out[i] = f2b(in[i]);
}

// ---------------------------------------------------------------------------
// bf16 MFMA GEMM: C[M,N] = A[M,K] * W[N,K]^T   (A, W bf16; C fp32 or bf16)
// BM=128, BN in {128,64}, BK=32. 256 threads = 4 waves.
// ---------------------------------------------------------------------------
template<int BN, bool OUT_BF16>
__global__ __launch_bounds__(256)
void gemm_mfma(const u16* __restrict__ A, int lda,
               const u16* __restrict__ W,
               void* __restrict__ Cout, int ldc, int Kd)
{
    constexpr int WX = (BN == 128) ? 2 : 1;
    constexpr int WY = 4 / WX;
    constexpr int MI = (128 / WY) / 16;
    constexpr int NI = (BN / WX) / 16;
    constexpr int BISS = BN * 64 / 4096;

    __shared__ u16 As[128 * 32];
    __shared__ u16 Bs[BN * 32];

    const int tid  = threadIdx.x;
    const int wave = tid >> 6;
    const int lane = tid & 63;
    const int wy = wave / WX, wx = wave % WX;
    const int by = blockIdx.y * 128;
    const int bx = blockIdx.x * BN;
    const int lr = lane & 15;
    const int lk = (lane >> 4) * 8;

    f32x4 acc[MI][NI];
#pragma unroll
    for (int i = 0; i < MI; i++)
#pragma unroll
        for (int j = 0; j < NI; j++) acc[i][j] = (f32x4){0.f, 0.f, 0.f, 0.f};

    const u16* Ag0 = A + (size_t)(by + (tid >> 2)) * lda + (tid & 3) * 8;
    const u16* Bg0 = W + (size_t)(bx + (tid >> 2)) * Kd + (tid & 3) * 8;
    u16* ldsA0 = &As[wave * 512];
    u16* ldsA1 = &As[2048 + wave * 512];
    u16* ldsB0 = &Bs[wave * 512];
    u16* ldsB1 = &Bs[2048 + wave * 512];

    for (int kt = 0; kt < Kd; kt += 32) {
        __syncthreads();
        cp16(Ag0 + kt, ldsA0);
        cp16(Ag0 + (size_t)64 * lda + kt, ldsA1);
        cp16(Bg0 + kt, ldsB0);
        if (BISS == 2) cp16(Bg0 + (size_t)64 * Kd + kt, ldsB1);
        __syncthreads();

        short8 af[MI], bf[NI];
#pragma unroll
        for (int mi = 0; mi < MI; mi++) {
            int m = wy * (MI * 16) + mi * 16 + lr;
            af[mi] = *(const short8*)&As[m * 32 + lk];
        }
#pragma unroll
        for (int ni = 0; ni < NI; ni++) {
            int n = wx * (NI * 16) + ni * 16 + lr;
            bf[ni] = *(const short8*)&Bs[n * 32 + lk];
        }
#pragma unroll
        for (int mi = 0; mi < MI; mi++)
#pragma unroll
            for (int ni = 0; ni < NI; ni++)
                acc[mi][ni] = __builtin_amdgcn_mfma_f32_16x16x32_bf16(
                    af[mi], bf[ni], acc[mi][ni], 0, 0, 0);
    }

#pragma unroll
    for (int mi = 0; mi < MI; mi++) {
#pragma unroll
        for (int ni = 0; ni < NI; ni++) {
            int col = bx + wx * (NI * 16) + ni * 16 + lr;
#pragma unroll
            for (int r = 0; r < 4; r++) {
                int row = by + wy * (MI * 16) + mi * 16 + (lane >> 4) * 4 + r;
                if (OUT_BF16)
                    ((u16*)Cout)[(size_t)row * ldc + col] = f2b(acc[mi][ni][r]);
                else
                    ((float*)Cout)[(size_t)row * ldc + col] = acc[mi][ni][r];
            }
        }
    }
}

// ---------------------------------------------------------------------------
// fp32 GEMM + bias + softplus: delta = softplus(A @ W^T + bias)
// ---------------------------------------------------------------------------
__global__ __launch_bounds__(128)
void gemm_delta(const float* __restrict__ A, int lda,
                const float* __restrict__ W, const float* __restrict__ bias,
                float* __restrict__ C, int Nn, int Kd)
{
    __shared__ float As[8][128];
    __shared__ float Ws[8][64];
    const int tid = threadIdx.x;
    const int tx = tid & 7;
    const int ty = tid >> 3;
    const int by = blockIdx.y * 128;
    const int bx = blockIdx.x * 64;

    float acc[8][8];
#pragma unroll
    for (int i = 0; i < 8; i++)
#pragma unroll
        for (int j = 0; j < 8; j++) acc[i][j] = 0.f;

    const int wcol = tid & 63;
    const int wk0  = (tid >> 6) * 4;

    for (int kt = 0; kt < Kd; kt += 8) {
        const float* Ap = A + (size_t)(by + tid) * lda + kt;
        float4 a0 = *(const float4*)(Ap);
        float4 a1 = *(const float4*)(Ap + 4);
        const float* Wp = W + (size_t)(bx + wcol) * Kd + kt + wk0;
        float4 w0 = *(const float4*)(Wp);
        __syncthreads();
        As[0][tid] = a0.x; As[1][tid] = a0.y; As[2][tid] = a0.z; As[3][tid] = a0.w;
        As[4][tid] = a1.x; As[5][tid] = a1.y; As[6][tid] = a1.z; As[7][tid] = a1.w;
        Ws[wk0 + 0][wcol] = w0.x; Ws[wk0 + 1][wcol] = w0.y;
        Ws[wk0 + 2][wcol] = w0.z; Ws[wk0 + 3][wcol] = w0.w;
        __syncthreads();
#pragma unroll
        for (int k = 0; k < 8; k++) {
            float4 av0 = *(const float4*)&As[k][ty * 8];
            float4 av1 = *(const float4*)&As[k][ty * 8 + 4];
            float4 wv0 = *(const float4*)&Ws[k][tx * 8];
            float4 wv1 = *(const float4*)&Ws[k][tx * 8 + 4];
            float a[8] = {av0.x, av0.y, av0.z, av0.w, av1.x, av1.y, av1.z, av1.w};
            float w[8] = {wv0.x, wv0.y, wv0.z, wv0.w, wv1.x, wv1.y, wv1.z, wv1.w};
#pragma unroll
            for (int i = 0; i < 8; i++)
#pragma unroll
                for (int j = 0; j < 8; j++)
                    acc[i][j] = fmaf(a[i], w[j], acc[i][j]);
        }
    }
#pragma unroll
    for (int i = 0; i < 8; i++) {
        float* Cp = C + (size_t)(by + ty * 8 + i) * Nn + bx + tx * 8;
#pragma unroll
        for (int j = 0; j < 8; j++) {
            float v = acc[i][j] + bias[bx + tx * 8 + j];
            Cp[j] = (v > 20.f) ? v : log1pf(__expf(v));
        }
    }
}

// ---------------------------------------------------------------------------
// Depthwise causal conv (K=4) + bias + SiLU. bf16 in (xz, stride 4096), bf16 out.
// ---------------------------------------------------------------------------
__global__ __launch_bounds__(256)
void conv_silu(const u16* __restrict__ xzb, const float* __restrict__ cw,
               const float* __restrict__ cb, u16* __restrict__ xpb)
{
    int idx = blockIdx.x * 256 + threadIdx.x;
    int e = idx & (ED_ - 1);
    int l = (idx >> 11) & (L_ - 1);
    int b = idx >> 22;
    const float w0 = cw[e * 4 + 0], w1 = cw[e * 4 + 1];
    const float w2 = cw[e * 4 + 2], w3 = cw[e * 4 + 3];
    const u16* base = xzb + (size_t)(b * L_) * 4096 + e;
    float x0 = (l >= 3) ? b2f(base[(size_t)(l - 3) * 4096]) : 0.f;
    float x1 = (l >= 2) ? b2f(base[(size_t)(l - 2) * 4096]) : 0.f;
    float x2 = (l >= 1) ? b2f(base[(size_t)(l - 1) * 4096]) : 0.f;
    float x3 = b2f(base[(size_t)l * 4096]);
    float v = cb[e] + w0 * x0 + w1 * x1 + w2 * x2 + w3 * x3;
    v = v / (1.f + __expf(-v));
    xpb[idx] = f2b(v);
}

// ---------------------------------------------------------------------------
// Chunked selective scan.
// pass1: per-chunk scan from h=0 -> hbuf (h_out per state), sumd (Sum delta).
// Block 256 = 16 channels x 16 lanes (4 states/lane). Grid (128, NCH, G).
// ---------------------------------------------------------------------------
__global__ __launch_bounds__(256)
void scan_pass1(const float* __restrict__ delta, const float* __restrict__ xdbl,
                const u16* __restrict__ xpb, const float* __restrict__ A_log,
                float* __restrict__ hbuf, float* __restrict__ sumd)
{
    const int tid = threadIdx.x;
    const int c = tid >> 4, j = tid & 15;
    const int b = blockIdx.z, ch = blockIdx.y;
    const int e = (blockIdx.x << 4) + c;
    const int l0 = ch * SCH_;

    float4 Al = *(const float4*)(A_log + (size_t)e * 64 + 4 * j);
    const float A0 = -__expf(Al.x), A1 = -__expf(Al.y);
    const float A2 = -__expf(Al.z), A3 = -__expf(Al.w);

    float h0 = 0.f, h1 = 0.f, h2 = 0.f, h3 = 0.f, sd = 0.f;
    size_t rowED  = ((size_t)(b * L_) + l0) * ED_ + e;
    size_t row192 = ((size_t)(b * L_) + l0) * 192;

    float  dv = delta[rowED];
    float4 Bv = *(const float4*)(xdbl + row192 + 64 + 4 * j);
    float  xv = b2f(xpb[rowED]);

    for (int s = 0; s < SCH_; ++s) {
        float dn = 0.f, xn = 0.f; float4 Bn = make_float4(0, 0, 0, 0);
        if (s + 1 < SCH_) {               // strict guard: no cross-chunk reads
            dn = delta[rowED + ED_];
            Bn = *(const float4*)(xdbl + row192 + 192 + 64 + 4 * j);
            xn = b2f(xpb[rowED + ED_]);
        }
        float dx = dv * xv;
        h0 = __expf(dv * A0) * h0 + dx * Bv.x;
        h1 = __expf(dv * A1) * h1 + dx * Bv.y;
        h2 = __expf(dv * A2) * h2 + dx * Bv.z;
        h3 = __expf(dv * A3) * h3 + dx * Bv.w;
        sd += dv;
        dv = dn; Bv = Bn; xv = xn;
        rowED += ED_; row192 += 192;
    }
    size_t slot = (((size_t)(b * NCH_ + ch) * ED_) + e) * 64 + 4 * j;
    *(float4*)(hbuf + slot) = make_float4(h0, h1, h2, h3);
    if (j == 0) sumd[(size_t)(b * NCH_ + ch) * ED_ + e] = sd;
}

// ---------------------------------------------------------------------------
// pass2: sequential combine over chunks; hbuf slot rewritten with h_in.
// One thread per (b,e,n) state. Grid G*512 blocks of 256.
// ---------------------------------------------------------------------------
__global__ __launch_bounds__(256)
void scan_pass2(float* __restrict__ hbuf, const float* __restrict__ sumd,
                const float* __restrict__ A_log)
{
    int idx = blockIdx.x * 256 + threadIdx.x;
    int n = idx & 63;
    int e = (idx >> 6) & (ED_ - 1);
    int b = idx >> 17;
    float A = -__expf(A_log[e * 64 + n]);
    float h = 0.f;
#pragma unroll
    for (int c = 0; c < NCH_; ++c) {
        size_t slot = (((size_t)(b * NCH_ + c) * ED_) + e) * 64 + n;
        float v  = hbuf[slot];
        float sd = sumd[(size_t)(b * NCH_ + c) * ED_ + e];
        hbuf[slot] = h;                   // h_in for chunk c
        h = __expf(A * sd) * h + v;
    }
}

// ---------------------------------------------------------------------------
// pass3: re-scan each chunk from h_in; C-dot + reduce; y = (acc + x*Dp)*silu(z)
// written bf16 IN PLACE over xpb. Grid (128, NCH, G).
// ---------------------------------------------------------------------------
__global__ __launch_bounds__(256)
void scan_pass3(const float* __restrict__ delta, const float* __restrict__ xdbl,
                const u16* __restrict__ xzb, u16* __restrict__ xpb,
                const float* __restrict__ A_log, const float* __restrict__ Dp,
                const float* __restrict__ hbuf)
{
    const int tid = threadIdx.x;
    const int c = tid >> 4, j = tid & 15;
    const int b = blockIdx.z, ch = blockIdx.y;
    const int e = (blockIdx.x << 4) + c;
    const int l0 = ch * SCH_;

    float4 Al = *(const float4*)(A_log + (size_t)e * 64 + 4 * j);
    const float A0 = -__expf(Al.x), A1 = -__expf(Al.y);
    const float A2 = -__expf(Al.z), A3 = -__expf(Al.w);
    const float dpe = Dp[e];

    size_t slot = (((size_t)(b * NCH_ + ch) * ED_) + e) * 64 + 4 * j;
    float4 hi = *(const float4*)(hbuf + slot);
    float h0 = hi.x, h1 = hi.y, h2 = hi.z, h3 = hi.w;

    size_t rowED  = ((size_t)(b * L_) + l0) * ED_ + e;
    size_t row192 = ((size_t)(b * L_) + l0) * 192;
    size_t rowZ   = ((size_t)(b * L_) + l0) * 4096 + ED_ + e;

    float  dv = delta[rowED];
    float4 Bv = *(const float4*)(xdbl + row192 + 64 + 4 * j);
    float4 Cv = *(const float4*)(xdbl + row192 + 128 + 4 * j);
    float  xv = b2f(xpb[rowED]);

    for (int s = 0; s < SCH_; ++s) {
        float dn = 0.f, xn = 0.f;
        float4 Bn = make_float4(0, 0, 0, 0), Cn = Bn;
        if (s + 1 < SCH_) {               // strict guard: next chunk's rows are
            dn = delta[rowED + ED_];      // being overwritten by another block
            Bn = *(const float4*)(xdbl + row192 + 192 + 64 + 4 * j);
            Cn = *(const float4*)(xdbl + row192 + 192 + 128 + 4 * j);
            xn = b2f(xpb[rowED + ED_]);
        }
        float dx = dv * xv;
        h0 = __expf(dv * A0) * h0 + dx * Bv.x;
        h1 = __expf(dv * A1) * h1 + dx * Bv.y;
        h2 = __expf(dv * A2) * h2 + dx * Bv.z;
        h3 = __expf(dv * A3) * h3 + dx * Bv.w;

        float acc = h0 * Cv.x + h1 * Cv.y + h2 * Cv.z + h3 * Cv.w;
        acc += __shfl_xor(acc, 1); acc += __shfl_xor(acc, 2);
        acc += __shfl_xor(acc, 4); acc += __shfl_xor(acc, 8);

        if (j == 0) {
            float z = b2f(xzb[rowZ]);
            float sz = z / (1.f + __expf(-z));
            xpb[rowED] = f2b((acc + xv * dpe) * sz);
        }
        dv = dn; Bv = Bn; Cv = Cn; xv = xn;
        rowED += ED_; row192 += 192; rowZ += 4096;
    }
}

// ---------------------------------------------------------------------------
// x = rmsnorm(t, norm_w) + x ; also writes bf16 copy of new x.
// ---------------------------------------------------------------------------
__global__ __launch_bounds__(256)
void rmsnorm_res(const float* __restrict__ t, const float* __restrict__ nw,
                 float* __restrict__ x, u16* __restrict__ xb)
{
    const int row = blockIdx.x;
    const int tid = threadIdx.x;
    const float* tr = t + (size_t)row * D_;
    float* xr = x + (size_t)row * D_;
    u16* xbr = xb + (size_t)row * D_;
    float4 v = *(const float4*)(tr + tid * 4);
    float ss = v.x * v.x + v.y * v.y + v.z * v.z + v.w * v.w;
#pragma unroll
    for (int m = 1; m < 64; m <<= 1) ss += __shfl_xor(ss, m);
    __shared__ float red[4];
    if ((tid & 63) == 0) red[tid >> 6] = ss;
    __syncthreads();
    float tot = red[0] + red[1] + red[2] + red[3];
    float scale = rsqrtf(tot * (1.f / (float)D_) + 1e-5f);
    float4 w = *(const float4*)(nw + tid * 4);
    float4 xo = *(const float4*)(xr + tid * 4);
    xo.x += v.x * scale * w.x;
    xo.y += v.y * scale * w.y;
    xo.z += v.z * scale * w.z;
    xo.w += v.w * scale * w.w;
    *(float4*)(xr + tid * 4) = xo;
    ushort4 hb;
    hb.x = f2b(xo.x); hb.y = f2b(xo.y); hb.z = f2b(xo.z); hb.w = f2b(xo.w);
    *(ushort4*)(xbr + tid * 4) = hb;
}

// ---------------------------------------------------------------------------
__global__ __launch_bounds__(256)
void head_kernel(const float* __restrict__ x, const float* __restrict__ Wh,
                 const float* __restrict__ bh, float* __restrict__ out)
{
    const int b = blockIdx.x >> 1, c = blockIdx.x & 1;
    const int tid = threadIdx.x;
    const float* xr = x + (size_t)(b * L_ + (L_ - 1)) * D_;
    const float* wr = Wh + c * D_;
    float4 xv = *(const float4*)(xr + tid * 4);
    float4 wv = *(const float4*)(wr + tid * 4);
    float s = xv.x * wv.x + xv.y * wv.y + xv.z * wv.z + xv.w * wv.w;
#pragma unroll
    for (int m = 1; m < 64; m <<= 1) s += __shfl_xor(s, m);
    __shared__ float red[4];
    if ((tid & 63) == 0) red[tid >> 6] = s;
    __syncthreads();
    if (tid == 0) out[b * 2 + c] = red[0] + red[1] + red[2] + red[3] + bh[c];
}

// ---------------------------------------------------------------------------
extern "C" void kernel_launch(void* const* d_in, const int* in_sizes, int n_in,
                              void* d_out, int out_size, void* d_ws, size_t ws_size,
                              hipStream_t stream)
{
    const float* x_in   = (const float*)d_in[0];
    const float* W_in   = (const float*)d_in[1];
    const float* conv_w = (const float*)d_in[2];
    const float* conv_b = (const float*)d_in[3];
    const float* W_x    = (const float*)d_in[4];
    const float* W_dt   = (const float*)d_in[5];
    const float* b_dt   = (const float*)d_in[6];
    const float* A_log  = (const float*)d_in[7];
    const float* D_p    = (const float*)d_in[8];
    const float* W_out  = (const float*)d_in[9];
    const float* norm_w = (const float*)d_in[10];
    const float* W_head = (const float*)d_in[11];
    const float* b_head = (const float*)d_in[12];
    float* out = (float*)d_out;

    // -------- bf16 weight region (fixed, head of ws) --------
    const size_t nWi = (size_t)NL_ * 2 * ED_ * D_;
    const size_t nWx = (size_t)NL_ * 192 * ED_;
    const size_t nWo = (size_t)NL_ * D_ * ED_;
    u16* Wi_b = (u16*)d_ws;
    u16* Wx_b = Wi_b + nWi;
    u16* Wo_b = Wx_b + nWx;
    size_t wbytes = ((nWi + nWx + nWo) * 2 + 255) & ~(size_t)255;
    char* gb = (char*)d_ws + wbytes;
    size_t usable = ws_size - wbytes;

    cast_bf16<<<(int)(nWi / 256), 256, 0, stream>>>(W_in, Wi_b, (int)nWi);
    cast_bf16<<<(int)(nWx / 256), 256, 0, stream>>>(W_x,  Wx_b, (int)nWx);
    cast_bf16<<<(int)(nWo / 256), 256, 0, stream>>>(W_out, Wo_b, (int)nWo);

    // per-batch: activations 49.5MB + hbuf 8.39MB + sumd 0.13MB = 60.4MB
    const size_t perB = (size_t)L_ * (D_ * 4 + 192 * 4 + ED_ * 4 + 4096 * 2 + ED_ * 2)
                      + (size_t)NCH_ * ED_ * 64 * 4 + (size_t)NCH_ * ED_ * 4;
    int G = 8;
    while (G > 1 && (size_t)G * perB > usable) G >>= 1;
    const int M = G * L_;

    // group-local layout
    float* x_cur = (float*)gb;                       // M*1024 f32
    float* xdbl  = x_cur + (size_t)M * D_;           // M*192  f32
    float* delta = xdbl + (size_t)M * 192;           // M*2048 f32
    u16*   x_b   = (u16*)delta;                      // alias (head of delta)
    u16*   xz_b  = (u16*)(delta + (size_t)M * ED_);  // M*4096 bf16
    u16*   xps_b = xz_b + (size_t)M * 4096;          // M*2048 bf16 (x, then y)
    float* hbuf  = (float*)(xps_b + (size_t)M * ED_);// G*NCH*ED*64 f32
    float* sumd  = hbuf + (size_t)G * NCH_ * ED_ * 64; // G*NCH*ED f32
    float* out_t = (float*)xz_b;                     // alias (GEMM3 out)

    for (int g0 = 0; g0 < B_; g0 += G) {
        const float* xg = x_in + (size_t)g0 * L_ * D_;
        hipMemcpyAsync(x_cur, xg, (size_t)M * D_ * sizeof(float),
                       hipMemcpyDeviceToDevice, stream);
        cast_bf16<<<(M * D_) / 256, 256, 0, stream>>>(xg, x_b, M * D_);

        for (int i = 0; i < NL_; ++i) {
            // 1) xz = x @ W_in^T  (M x 4096 x 1024), bf16 out
            gemm_mfma<128, true><<<dim3(4096 / 128, M / 128), 256, 0, stream>>>(
                x_b, D_, Wi_b + (size_t)i * 2 * ED_ * D_, xz_b, 4096, D_);
            // 2) xps = silu(conv(xp) + cb), bf16
            conv_silu<<<(M * ED_) / 256, 256, 0, stream>>>(
                xz_b, conv_w + (size_t)i * ED_ * 4, conv_b + (size_t)i * ED_, xps_b);
            // 3) xdbl = xps @ W_x^T  (M x 192 x 2048), fp32 out
            gemm_mfma<64, false><<<dim3(192 / 64, M / 128), 256, 0, stream>>>(
                xps_b, ED_, Wx_b + (size_t)i * 192 * ED_, xdbl, 192, ED_);
            // 4) delta = softplus(dt @ W_dt^T + b_dt)  (M x 2048 x 64), fp32
            gemm_delta<<<dim3(ED_ / 64, M / 128), 128, 0, stream>>>(
                xdbl, 192, W_dt + (size_t)i * ED_ * 64, b_dt + (size_t)i * ED_,
                delta, ED_, 64);
            // 5) chunked scan
            scan_pass1<<<dim3(128, NCH_, G), 256, 0, stream>>>(
                delta, xdbl, xps_b, A_log + (size_t)i * ED_ * 64, hbuf, sumd);
            scan_pass2<<<G * 512, 256, 0, stream>>>(
                hbuf, sumd, A_log + (size_t)i * ED_ * 64);
            scan_pass3<<<dim3(128, NCH_, G), 256, 0, stream>>>(
                delta, xdbl, xz_b, xps_b,
                A_log + (size_t)i * ED_ * 64, D_p + (size_t)i * ED_, hbuf);
            // 6) out_t = y @ W_out^T  (M x 1024 x 2048), fp32 out
            gemm_mfma<128, false><<<dim3(D_ / 128, M / 128), 256, 0, stream>>>(
                xps_b, ED_, Wo_b + (size_t)i * D_ * ED_, out_t, D_, ED_);
            // 7) x = rmsnorm(out_t) + x  (+ bf16 copy)
            rmsnorm_res<<<M, 256, 0, stream>>>(out_t, norm_w + (size_t)i * D_,
                                               x_cur, x_b);
        }
        head_kernel<<<G * NC_, 256, 0, stream>>>(x_cur, W_head, b_head,
                                                 out + (size_t)g0 * NC_);
    }
}

// Round 5
// 7099.186 us; speedup vs baseline: 3.2917x; 1.0493x over previous
//
#include <hip/hip_runtime.h>
#include <math.h>

#define B_ 8
#define L_ 2048
#define D_ 1024
#define ED_ 2048
#define NL_ 3
#define NC_ 2
#define SCH_ 128              // scan chunk length
#define NCH_ (L_ / SCH_)      // 16 chunks

typedef unsigned short u16;
typedef unsigned int u32;
typedef __attribute__((ext_vector_type(8))) short short8;
typedef __attribute__((ext_vector_type(4))) float f32x4;

__device__ __forceinline__ u16 f2b(float f) {
    u32 u = __float_as_uint(f);
    u = (u + 0x7FFFu + ((u >> 16) & 1u)) >> 16;
    return (u16)u;
}
__device__ __forceinline__ float b2f(u16 h) {
    return __uint_as_float(((u32)h) << 16);
}
__device__ __forceinline__ void cp16(const void* g, void* l) {
    __builtin_amdgcn_global_load_lds((const __attribute__((address_space(1))) u32*)g,
                                     (__attribute__((address_space(3))) u32*)l,
                                     16, 0, 0);
}

// ---------------------------------------------------------------------------
// fp32 -> bf16 cast (RNE)
// ---------------------------------------------------------------------------
__global__ __launch_bounds__(256)
void cast_bf16(const float* __restrict__ in, u16* __restrict__ out, int n)
{
    int i = blockIdx.x * 256 + threadIdx.x;
    if (i < n) out[i] = f2b(in[i]);
}

// ---------------------------------------------------------------------------
// bf16 MFMA GEMM: C[M,N] = A[M,K] * W[N,K]^T   (A, W bf16; C fp32 or bf16)
// BM=128, BN in {128,64}, BK=32. 256 threads = 4 waves.
// ---------------------------------------------------------------------------
template<int BN, bool OUT_BF16>
__global__ __launch_bounds__(256)
void gemm_mfma(const u16* __restrict__ A, int lda,
               const u16* __restrict__ W,
               void* __restrict__ Cout, int ldc, int Kd)
{
    constexpr int WX = (BN == 128) ? 2 : 1;
    constexpr int WY = 4 / WX;
    constexpr int MI = (128 / WY) / 16;
    constexpr int NI = (BN / WX) / 16;
    constexpr int BISS = BN * 64 / 4096;

    __shared__ u16 As[128 * 32];
    __shared__ u16 Bs[BN * 32];

    const int tid  = threadIdx.x;
    const int wave = tid >> 6;
    const int lane = tid & 63;
    const int wy = wave / WX, wx = wave % WX;
    const int by = blockIdx.y * 128;
    const int bx = blockIdx.x * BN;
    const int lr = lane & 15;
    const int lk = (lane >> 4) * 8;

    f32x4 acc[MI][NI];
#pragma unroll
    for (int i = 0; i < MI; i++)
#pragma unroll
        for (int j = 0; j < NI; j++) acc[i][j] = (f32x4){0.f, 0.f, 0.f, 0.f};

    const u16* Ag0 = A + (size_t)(by + (tid >> 2)) * lda + (tid & 3) * 8;
    const u16* Bg0 = W + (size_t)(bx + (tid >> 2)) * Kd + (tid & 3) * 8;
    u16* ldsA0 = &As[wave * 512];
    u16* ldsA1 = &As[2048 + wave * 512];
    u16* ldsB0 = &Bs[wave * 512];
    u16* ldsB1 = &Bs[2048 + wave * 512];

    for (int kt = 0; kt < Kd; kt += 32) {
        __syncthreads();
        cp16(Ag0 + kt, ldsA0);
        cp16(Ag0 + (size_t)64 * lda + kt, ldsA1);
        cp16(Bg0 + kt, ldsB0);
        if (BISS == 2) cp16(Bg0 + (size_t)64 * Kd + kt, ldsB1);
        __syncthreads();

        short8 af[MI], bf[NI];
#pragma unroll
        for (int mi = 0; mi < MI; mi++) {
            int m = wy * (MI * 16) + mi * 16 + lr;
            af[mi] = *(const short8*)&As[m * 32 + lk];
        }
#pragma unroll
        for (int ni = 0; ni < NI; ni++) {
            int n = wx * (NI * 16) + ni * 16 + lr;
            bf[ni] = *(const short8*)&Bs[n * 32 + lk];
        }
#pragma unroll
        for (int mi = 0; mi < MI; mi++)
#pragma unroll
            for (int ni = 0; ni < NI; ni++)
                acc[mi][ni] = __builtin_amdgcn_mfma_f32_16x16x32_bf16(
                    af[mi], bf[ni], acc[mi][ni], 0, 0, 0);
    }

#pragma unroll
    for (int mi = 0; mi < MI; mi++) {
#pragma unroll
        for (int ni = 0; ni < NI; ni++) {
            int col = bx + wx * (NI * 16) + ni * 16 + lr;
#pragma unroll
            for (int r = 0; r < 4; r++) {
                int row = by + wy * (MI * 16) + mi * 16 + (lane >> 4) * 4 + r;
                if (OUT_BF16)
                    ((u16*)Cout)[(size_t)row * ldc + col] = f2b(acc[mi][ni][r]);
                else
                    ((float*)Cout)[(size_t)row * ldc + col] = acc[mi][ni][r];
            }
        }
    }
}

// ---------------------------------------------------------------------------
// fp32 GEMM + bias + softplus: delta = softplus(A @ W^T + bias)
// ---------------------------------------------------------------------------
__global__ __launch_bounds__(128)
void gemm_delta(const float* __restrict__ A, int lda,
                const float* __restrict__ W, const float* __restrict__ bias,
                float* __restrict__ C, int Nn, int Kd)
{
    __shared__ float As[8][128];
    __shared__ float Ws[8][64];
    const int tid = threadIdx.x;
    const int tx = tid & 7;
    const int ty = tid >> 3;
    const int by = blockIdx.y * 128;
    const int bx = blockIdx.x * 64;

    float acc[8][8];
#pragma unroll
    for (int i = 0; i < 8; i++)
#pragma unroll
        for (int j = 0; j < 8; j++) acc[i][j] = 0.f;

    const int wcol = tid & 63;
    const int wk0  = (tid >> 6) * 4;

    for (int kt = 0; kt < Kd; kt += 8) {
        const float* Ap = A + (size_t)(by + tid) * lda + kt;
        float4 a0 = *(const float4*)(Ap);
        float4 a1 = *(const float4*)(Ap + 4);
        const float* Wp = W + (size_t)(bx + wcol) * Kd + kt + wk0;
        float4 w0 = *(const float4*)(Wp);
        __syncthreads();
        As[0][tid] = a0.x; As[1][tid] = a0.y; As[2][tid] = a0.z; As[3][tid] = a0.w;
        As[4][tid] = a1.x; As[5][tid] = a1.y; As[6][tid] = a1.z; As[7][tid] = a1.w;
        Ws[wk0 + 0][wcol] = w0.x; Ws[wk0 + 1][wcol] = w0.y;
        Ws[wk0 + 2][wcol] = w0.z; Ws[wk0 + 3][wcol] = w0.w;
        __syncthreads();
#pragma unroll
        for (int k = 0; k < 8; k++) {
            float4 av0 = *(const float4*)&As[k][ty * 8];
            float4 av1 = *(const float4*)&As[k][ty * 8 + 4];
            float4 wv0 = *(const float4*)&Ws[k][tx * 8];
            float4 wv1 = *(const float4*)&Ws[k][tx * 8 + 4];
            float a[8] = {av0.x, av0.y, av0.z, av0.w, av1.x, av1.y, av1.z, av1.w};
            float w[8] = {wv0.x, wv0.y, wv0.z, wv0.w, wv1.x, wv1.y, wv1.z, wv1.w};
#pragma unroll
            for (int i = 0; i < 8; i++)
#pragma unroll
                for (int j = 0; j < 8; j++)
                    acc[i][j] = fmaf(a[i], w[j], acc[i][j]);
        }
    }
#pragma unroll
    for (int i = 0; i < 8; i++) {
        float* Cp = C + (size_t)(by + ty * 8 + i) * Nn + bx + tx * 8;
#pragma unroll
        for (int j = 0; j < 8; j++) {
            float v = acc[i][j] + bias[bx + tx * 8 + j];
            Cp[j] = (v > 20.f) ? v : log1pf(__expf(v));
        }
    }
}

// ---------------------------------------------------------------------------
// Depthwise causal conv (K=4) + bias + SiLU. bf16 in (xz, stride 4096), bf16 out.
// ---------------------------------------------------------------------------
__global__ __launch_bounds__(256)
void conv_silu(const u16* __restrict__ xzb, const float* __restrict__ cw,
               const float* __restrict__ cb, u16* __restrict__ xpb)
{
    int idx = blockIdx.x * 256 + threadIdx.x;
    int e = idx & (ED_ - 1);
    int l = (idx >> 11) & (L_ - 1);
    int b = idx >> 22;
    const float w0 = cw[e * 4 + 0], w1 = cw[e * 4 + 1];
    const float w2 = cw[e * 4 + 2], w3 = cw[e * 4 + 3];
    const u16* base = xzb + (size_t)(b * L_) * 4096 + e;
    float x0 = (l >= 3) ? b2f(base[(size_t)(l - 3) * 4096]) : 0.f;
    float x1 = (l >= 2) ? b2f(base[(size_t)(l - 2) * 4096]) : 0.f;
    float x2 = (l >= 1) ? b2f(base[(size_t)(l - 1) * 4096]) : 0.f;
    float x3 = b2f(base[(size_t)l * 4096]);
    float v = cb[e] + w0 * x0 + w1 * x1 + w2 * x2 + w3 * x3;
    v = v / (1.f + __expf(-v));
    xpb[idx] = f2b(v);
}

// ---------------------------------------------------------------------------
// Chunked selective scan.
// pass1: per-chunk scan from h=0 -> hbuf (h_out), sumd. Grid (128, NCH-1, G)
// (last chunk's h_out/sumd are never consumed -> not computed).
// Steady-state loop peeled: unconditional prefetch for s < SCH-1.
// ---------------------------------------------------------------------------
__global__ __launch_bounds__(256)
void scan_pass1(const float* __restrict__ delta, const float* __restrict__ xdbl,
                const u16* __restrict__ xpb, const float* __restrict__ A_log,
                float* __restrict__ hbuf, float* __restrict__ sumd)
{
    const int tid = threadIdx.x;
    const int c = tid >> 4, j = tid & 15;
    const int b = blockIdx.z, ch = blockIdx.y;
    const int e = (blockIdx.x << 4) + c;
    const int l0 = ch * SCH_;

    float4 Al = *(const float4*)(A_log + (size_t)e * 64 + 4 * j);
    const float A0 = -__expf(Al.x), A1 = -__expf(Al.y);
    const float A2 = -__expf(Al.z), A3 = -__expf(Al.w);

    float h0 = 0.f, h1 = 0.f, h2 = 0.f, h3 = 0.f, sd = 0.f;
    size_t rowED  = ((size_t)(b * L_) + l0) * ED_ + e;
    size_t row192 = ((size_t)(b * L_) + l0) * 192;

    float  dv = delta[rowED];
    float4 Bv = *(const float4*)(xdbl + row192 + 64 + 4 * j);
    float  xv = b2f(xpb[rowED]);

#pragma unroll 2
    for (int s = 0; s < SCH_ - 1; ++s) {
        float  dn = delta[rowED + ED_];
        float4 Bn = *(const float4*)(xdbl + row192 + 192 + 64 + 4 * j);
        float  xn = b2f(xpb[rowED + ED_]);

        float dx = dv * xv;
        h0 = __expf(dv * A0) * h0 + dx * Bv.x;
        h1 = __expf(dv * A1) * h1 + dx * Bv.y;
        h2 = __expf(dv * A2) * h2 + dx * Bv.z;
        h3 = __expf(dv * A3) * h3 + dx * Bv.w;
        sd += dv;
        dv = dn; Bv = Bn; xv = xn;
        rowED += ED_; row192 += 192;
    }
    {   // final step, no prefetch
        float dx = dv * xv;
        h0 = __expf(dv * A0) * h0 + dx * Bv.x;
        h1 = __expf(dv * A1) * h1 + dx * Bv.y;
        h2 = __expf(dv * A2) * h2 + dx * Bv.z;
        h3 = __expf(dv * A3) * h3 + dx * Bv.w;
        sd += dv;
    }
    size_t slot = (((size_t)(b * NCH_ + ch) * ED_) + e) * 64 + 4 * j;
    *(float4*)(hbuf + slot) = make_float4(h0, h1, h2, h3);
    if (j == 0) sumd[(size_t)(b * NCH_ + ch) * ED_ + e] = sd;
}

// ---------------------------------------------------------------------------
// pass2: sequential combine; hbuf[c] rewritten with h_in for chunk c.
// Chunk NCH-1's h_out/sumd are never read (not written by pass1).
// ---------------------------------------------------------------------------
__global__ __launch_bounds__(256)
void scan_pass2(float* __restrict__ hbuf, const float* __restrict__ sumd,
                const float* __restrict__ A_log)
{
    int idx = blockIdx.x * 256 + threadIdx.x;
    int n = idx & 63;
    int e = (idx >> 6) & (ED_ - 1);
    int b = idx >> 17;
    float A = -__expf(A_log[e * 64 + n]);
    float h = 0.f;
#pragma unroll
    for (int c = 0; c < NCH_; ++c) {
        size_t slot = (((size_t)(b * NCH_ + c) * ED_) + e) * 64 + n;
        float v = 0.f, sd = 0.f;
        if (c < NCH_ - 1) {
            v  = hbuf[slot];
            sd = sumd[(size_t)(b * NCH_ + c) * ED_ + e];
        }
        hbuf[slot] = h;                   // h_in for chunk c
        if (c < NCH_ - 1) h = __expf(A * sd) * h + v;
    }
}

// ---------------------------------------------------------------------------
// pass3: re-scan each chunk from h_in; C-dot + reduce; y = (acc + x*Dp)*silu(z)
// written bf16 IN PLACE over xpb. Grid (128, NCH, G). Peeled final step.
// ---------------------------------------------------------------------------
__global__ __launch_bounds__(256)
void scan_pass3(const float* __restrict__ delta, const float* __restrict__ xdbl,
                const u16* __restrict__ xzb, u16* __restrict__ xpb,
                const float* __restrict__ A_log, const float* __restrict__ Dp,
                const float* __restrict__ hbuf)
{
    const int tid = threadIdx.x;
    const int c = tid >> 4, j = tid & 15;
    const int b = blockIdx.z, ch = blockIdx.y;
    const int e = (blockIdx.x << 4) + c;
    const int l0 = ch * SCH_;

    float4 Al = *(const float4*)(A_log + (size_t)e * 64 + 4 * j);
    const float A0 = -__expf(Al.x), A1 = -__expf(Al.y);
    const float A2 = -__expf(Al.z), A3 = -__expf(Al.w);
    const float dpe = Dp[e];

    size_t slot = (((size_t)(b * NCH_ + ch) * ED_) + e) * 64 + 4 * j;
    float4 hi = *(const float4*)(hbuf + slot);
    float h0 = hi.x, h1 = hi.y, h2 = hi.z, h3 = hi.w;

    size_t rowED  = ((size_t)(b * L_) + l0) * ED_ + e;
    size_t row192 = ((size_t)(b * L_) + l0) * 192;
    size_t rowZ   = ((size_t)(b * L_) + l0) * 4096 + ED_ + e;

    float  dv = delta[rowED];
    float4 Bv = *(const float4*)(xdbl + row192 + 64 + 4 * j);
    float4 Cv = *(const float4*)(xdbl + row192 + 128 + 4 * j);
    float  xv = b2f(xpb[rowED]);

#pragma unroll 2
    for (int s = 0; s < SCH_ - 1; ++s) {
        float  dn = delta[rowED + ED_];
        float4 Bn = *(const float4*)(xdbl + row192 + 192 + 64 + 4 * j);
        float4 Cn = *(const float4*)(xdbl + row192 + 192 + 128 + 4 * j);
        float  xn = b2f(xpb[rowED + ED_]);

        float dx = dv * xv;
        h0 = __expf(dv * A0) * h0 + dx * Bv.x;
        h1 = __expf(dv * A1) * h1 + dx * Bv.y;
        h2 = __expf(dv * A2) * h2 + dx * Bv.z;
        h3 = __expf(dv * A3) * h3 + dx * Bv.w;

        float acc = h0 * Cv.x + h1 * Cv.y + h2 * Cv.z + h3 * Cv.w;
        acc += __shfl_xor(acc, 1); acc += __shfl_xor(acc, 2);
        acc += __shfl_xor(acc, 4); acc += __shfl_xor(acc, 8);

        if (j == 0) {
            float z = b2f(xzb[rowZ]);
            float sz = z / (1.f + __expf(-z));
            xpb[rowED] = f2b((acc + xv * dpe) * sz);   // after row l+1 prefetch
        }
        dv = dn; Bv = Bn; Cv = Cn; xv = xn;
        rowED += ED_; row192 += 192; rowZ += 4096;
    }
    {   // final step, no prefetch
        float dx = dv * xv;
        h0 = __expf(dv * A0) * h0 + dx * Bv.x;
        h1 = __expf(dv * A1) * h1 + dx * Bv.y;
        h2 = __expf(dv * A2) * h2 + dx * Bv.z;
        h3 = __expf(dv * A3) * h3 + dx * Bv.w;

        float acc = h0 * Cv.x + h1 * Cv.y + h2 * Cv.z + h3 * Cv.w;
        acc += __shfl_xor(acc, 1); acc += __shfl_xor(acc, 2);
        acc += __shfl_xor(acc, 4); acc += __shfl_xor(acc, 8);

        if (j == 0) {
            float z = b2f(xzb[rowZ]);
            float sz = z / (1.f + __expf(-z));
            xpb[rowED] = f2b((acc + xv * dpe) * sz);
        }
    }
}

// ---------------------------------------------------------------------------
// x = rmsnorm(t, norm_w) + x ; also writes bf16 copy of new x.
// ---------------------------------------------------------------------------
__global__ __launch_bounds__(256)
void rmsnorm_res(const float* __restrict__ t, const float* __restrict__ nw,
                 float* __restrict__ x, u16* __restrict__ xb)
{
    const int row = blockIdx.x;
    const int tid = threadIdx.x;
    const float* tr = t + (size_t)row * D_;
    float* xr = x + (size_t)row * D_;
    u16* xbr = xb + (size_t)row * D_;
    float4 v = *(const float4*)(tr + tid * 4);
    float ss = v.x * v.x + v.y * v.y + v.z * v.z + v.w * v.w;
#pragma unroll
    for (int m = 1; m < 64; m <<= 1) ss += __shfl_xor(ss, m);
    __shared__ float red[4];
    if ((tid & 63) == 0) red[tid >> 6] = ss;
    __syncthreads();
    float tot = red[0] + red[1] + red[2] + red[3];
    float scale = rsqrtf(tot * (1.f / (float)D_) + 1e-5f);
    float4 w = *(const float4*)(nw + tid * 4);
    float4 xo = *(const float4*)(xr + tid * 4);
    xo.x += v.x * scale * w.x;
    xo.y += v.y * scale * w.y;
    xo.z += v.z * scale * w.z;
    xo.w += v.w * scale * w.w;
    *(float4*)(xr + tid * 4) = xo;
    ushort4 hb;
    hb.x = f2b(xo.x); hb.y = f2b(xo.y); hb.z = f2b(xo.z); hb.w = f2b(xo.w);
    *(ushort4*)(xbr + tid * 4) = hb;
}

// ---------------------------------------------------------------------------
__global__ __launch_bounds__(256)
void head_kernel(const float* __restrict__ x, const float* __restrict__ Wh,
                 const float* __restrict__ bh, float* __restrict__ out)
{
    const int b = blockIdx.x >> 1, c = blockIdx.x & 1;
    const int tid = threadIdx.x;
    const float* xr = x + (size_t)(b * L_ + (L_ - 1)) * D_;
    const float* wr = Wh + c * D_;
    float4 xv = *(const float4*)(xr + tid * 4);
    float4 wv = *(const float4*)(wr + tid * 4);
    float s = xv.x * wv.x + xv.y * wv.y + xv.z * wv.z + xv.w * wv.w;
#pragma unroll
    for (int m = 1; m < 64; m <<= 1) s += __shfl_xor(s, m);
    __shared__ float red[4];
    if ((tid & 63) == 0) red[tid >> 6] = s;
    __syncthreads();
    if (tid == 0) out[b * 2 + c] = red[0] + red[1] + red[2] + red[3] + bh[c];
}

// ---------------------------------------------------------------------------
extern "C" void kernel_launch(void* const* d_in, const int* in_sizes, int n_in,
                              void* d_out, int out_size, void* d_ws, size_t ws_size,
                              hipStream_t stream)
{
    const float* x_in   = (const float*)d_in[0];
    const float* W_in   = (const float*)d_in[1];
    const float* conv_w = (const float*)d_in[2];
    const float* conv_b = (const float*)d_in[3];
    const float* W_x    = (const float*)d_in[4];
    const float* W_dt   = (const float*)d_in[5];
    const float* b_dt   = (const float*)d_in[6];
    const float* A_log  = (const float*)d_in[7];
    const float* D_p    = (const float*)d_in[8];
    const float* W_out  = (const float*)d_in[9];
    const float* norm_w = (const float*)d_in[10];
    const float* W_head = (const float*)d_in[11];
    const float* b_head = (const float*)d_in[12];
    float* out = (float*)d_out;

    // -------- bf16 weight region (fixed, head of ws) --------
    const size_t nWi = (size_t)NL_ * 2 * ED_ * D_;
    const size_t nWx = (size_t)NL_ * 192 * ED_;
    const size_t nWo = (size_t)NL_ * D_ * ED_;
    u16* Wi_b = (u16*)d_ws;
    u16* Wx_b = Wi_b + nWi;
    u16* Wo_b = Wx_b + nWx;
    size_t wbytes = ((nWi + nWx + nWo) * 2 + 255) & ~(size_t)255;
    char* gb = (char*)d_ws + wbytes;
    size_t usable = ws_size - wbytes;

    cast_bf16<<<(int)(nWi / 256), 256, 0, stream>>>(W_in, Wi_b, (int)nWi);
    cast_bf16<<<(int)(nWx / 256), 256, 0, stream>>>(W_x,  Wx_b, (int)nWx);
    cast_bf16<<<(int)(nWo / 256), 256, 0, stream>>>(W_out, Wo_b, (int)nWo);

    // per-batch: activations 49.5MB + hbuf 8.39MB + sumd 0.13MB = 60.4MB
    const size_t perB = (size_t)L_ * (D_ * 4 + 192 * 4 + ED_ * 4 + 4096 * 2 + ED_ * 2)
                      + (size_t)NCH_ * ED_ * 64 * 4 + (size_t)NCH_ * ED_ * 4;
    int G = 8;
    while (G > 1 && (size_t)G * perB > usable) G >>= 1;
    const int M = G * L_;

    // group-local layout
    float* x_cur = (float*)gb;                       // M*1024 f32
    float* xdbl  = x_cur + (size_t)M * D_;           // M*192  f32
    float* delta = xdbl + (size_t)M * 192;           // M*2048 f32
    u16*   x_b   = (u16*)delta;                      // alias (head of delta)
    u16*   xz_b  = (u16*)(delta + (size_t)M * ED_);  // M*4096 bf16
    u16*   xps_b = xz_b + (size_t)M * 4096;          // M*2048 bf16 (x, then y)
    float* hbuf  = (float*)(xps_b + (size_t)M * ED_);// G*NCH*ED*64 f32
    float* sumd  = hbuf + (size_t)G * NCH_ * ED_ * 64; // G*NCH*ED f32
    float* out_t = (float*)xz_b;                     // alias (GEMM3 out)

    for (int g0 = 0; g0 < B_; g0 += G) {
        const float* xg = x_in + (size_t)g0 * L_ * D_;
        hipMemcpyAsync(x_cur, xg, (size_t)M * D_ * sizeof(float),
                       hipMemcpyDeviceToDevice, stream);
        cast_bf16<<<(M * D_) / 256, 256, 0, stream>>>(xg, x_b, M * D_);

        for (int i = 0; i < NL_; ++i) {
            // 1) xz = x @ W_in^T  (M x 4096 x 1024), bf16 out
            gemm_mfma<128, true><<<dim3(4096 / 128, M / 128), 256, 0, stream>>>(
                x_b, D_, Wi_b + (size_t)i * 2 * ED_ * D_, xz_b, 4096, D_);
            // 2) xps = silu(conv(xp) + cb), bf16
            conv_silu<<<(M * ED_) / 256, 256, 0, stream>>>(
                xz_b, conv_w + (size_t)i * ED_ * 4, conv_b + (size_t)i * ED_, xps_b);
            // 3) xdbl = xps @ W_x^T  (M x 192 x 2048), fp32 out
            gemm_mfma<64, false><<<dim3(192 / 64, M / 128), 256, 0, stream>>>(
                xps_b, ED_, Wx_b + (size_t)i * 192 * ED_, xdbl, 192, ED_);
            // 4) delta = softplus(dt @ W_dt^T + b_dt)  (M x 2048 x 64), fp32
            gemm_delta<<<dim3(ED_ / 64, M / 128), 128, 0, stream>>>(
                xdbl, 192, W_dt + (size_t)i * ED_ * 64, b_dt + (size_t)i * ED_,
                delta, ED_, 64);
            // 5) chunked scan
            scan_pass1<<<dim3(128, NCH_ - 1, G), 256, 0, stream>>>(
                delta, xdbl, xps_b, A_log + (size_t)i * ED_ * 64, hbuf, sumd);
            scan_pass2<<<G * 512, 256, 0, stream>>>(
                hbuf, sumd, A_log + (size_t)i * ED_ * 64);
            scan_pass3<<<dim3(128, NCH_, G), 256, 0, stream>>>(
                delta, xdbl, xz_b, xps_b,
                A_log + (size_t)i * ED_ * 64, D_p + (size_t)i * ED_, hbuf);
            // 6) out_t = y @ W_out^T  (M x 1024 x 2048), fp32 out
            gemm_mfma<128, false><<<dim3(D_ / 128, M / 128), 256, 0, stream>>>(
                xps_b, ED_, Wo_b + (size_t)i * D_ * ED_, out_t, D_, ED_);
            // 7) x = rmsnorm(out_t) + x  (+ bf16 copy)
            rmsnorm_res<<<M, 256, 0, stream>>>(out_t, norm_w + (size_t)i * D_,
                                               x_cur, x_b);
        }
        head_kernel<<<G * NC_, 256, 0, stream>>>(x_cur, W_head, b_head,
                                                 out + (size_t)g0 * NC_);
    }
}

// Round 6
// 5974.269 us; speedup vs baseline: 3.9115x; 1.1883x over previous
//
#include <hip/hip_runtime.h>
#include <math.h>

#define B_ 8
#define L_ 2048
#define D_ 1024
#define ED_ 2048
#define NL_ 3
#define NC_ 2
#define SCH_ 128              // scan chunk length
#define NCH_ (L_ / SCH_)      // 16 chunks

typedef unsigned short u16;
typedef unsigned int u32;
typedef __attribute__((ext_vector_type(8))) short short8;
typedef __attribute__((ext_vector_type(4))) float f32x4;

#define LOG2E_ 1.44269504088896f

__device__ __forceinline__ u16 f2b(float f) {
    u32 u = __float_as_uint(f);
    u = (u + 0x7FFFu + ((u >> 16) & 1u)) >> 16;
    return (u16)u;
}
__device__ __forceinline__ float b2f(u16 h) {
    return __uint_as_float(((u32)h) << 16);
}
__device__ __forceinline__ float fexp2(float x) {
#if __has_builtin(__builtin_amdgcn_exp2f)
    return __builtin_amdgcn_exp2f(x);
#else
    return exp2f(x);
#endif
}
__device__ __forceinline__ void cp16(const void* g, void* l) {
    __builtin_amdgcn_global_load_lds((const __attribute__((address_space(1))) u32*)g,
                                     (__attribute__((address_space(3))) u32*)l,
                                     16, 0, 0);
}

// ---------------------------------------------------------------------------
// fp32 -> bf16 cast (RNE)
// ---------------------------------------------------------------------------
__global__ __launch_bounds__(256)
void cast_bf16(const float* __restrict__ in, u16* __restrict__ out, int n)
{
    int i = blockIdx.x * 256 + threadIdx.x;
    if (i < n) out[i] = f2b(in[i]);
}

// ---------------------------------------------------------------------------
// strided cast: dtb[m, 0:64] = bf16(xdbl[m, 0:64]) with xdbl row stride 192
// ---------------------------------------------------------------------------
__global__ __launch_bounds__(256)
void cast_dt(const float* __restrict__ xdbl, u16* __restrict__ dtb)
{
    int idx = blockIdx.x * 256 + threadIdx.x;   // M*64 threads
    int m = idx >> 6, r = idx & 63;
    dtb[idx] = f2b(xdbl[(size_t)m * 192 + r]);
}

// ---------------------------------------------------------------------------
// bf16 MFMA GEMM: C[M,N] = A[M,K] * W[N,K]^T   (A, W bf16)
// EPI: 0 = fp32 store, 1 = bf16 store, 2 = softplus(acc + bias) fp32 store
// BM=128, BN in {128,64}, BK=32. 256 threads = 4 waves.
// ---------------------------------------------------------------------------
template<int BN, int EPI>
__global__ __launch_bounds__(256)
void gemm_mfma(const u16* __restrict__ A, int lda,
               const u16* __restrict__ W, const float* __restrict__ bias,
               void* __restrict__ Cout, int ldc, int Kd)
{
    constexpr int WX = (BN == 128) ? 2 : 1;
    constexpr int WY = 4 / WX;
    constexpr int MI = (128 / WY) / 16;
    constexpr int NI = (BN / WX) / 16;
    constexpr int BISS = BN * 64 / 4096;

    __shared__ u16 As[128 * 32];
    __shared__ u16 Bs[BN * 32];

    const int tid  = threadIdx.x;
    const int wave = tid >> 6;
    const int lane = tid & 63;
    const int wy = wave / WX, wx = wave % WX;
    const int by = blockIdx.y * 128;
    const int bx = blockIdx.x * BN;
    const int lr = lane & 15;
    const int lk = (lane >> 4) * 8;

    f32x4 acc[MI][NI];
#pragma unroll
    for (int i = 0; i < MI; i++)
#pragma unroll
        for (int j = 0; j < NI; j++) acc[i][j] = (f32x4){0.f, 0.f, 0.f, 0.f};

    const u16* Ag0 = A + (size_t)(by + (tid >> 2)) * lda + (tid & 3) * 8;
    const u16* Bg0 = W + (size_t)(bx + (tid >> 2)) * Kd + (tid & 3) * 8;
    u16* ldsA0 = &As[wave * 512];
    u16* ldsA1 = &As[2048 + wave * 512];
    u16* ldsB0 = &Bs[wave * 512];
    u16* ldsB1 = &Bs[2048 + wave * 512];

    for (int kt = 0; kt < Kd; kt += 32) {
        __syncthreads();
        cp16(Ag0 + kt, ldsA0);
        cp16(Ag0 + (size_t)64 * lda + kt, ldsA1);
        cp16(Bg0 + kt, ldsB0);
        if (BISS == 2) cp16(Bg0 + (size_t)64 * Kd + kt, ldsB1);
        __syncthreads();

        short8 af[MI], bf[NI];
#pragma unroll
        for (int mi = 0; mi < MI; mi++) {
            int m = wy * (MI * 16) + mi * 16 + lr;
            af[mi] = *(const short8*)&As[m * 32 + lk];
        }
#pragma unroll
        for (int ni = 0; ni < NI; ni++) {
            int n = wx * (NI * 16) + ni * 16 + lr;
            bf[ni] = *(const short8*)&Bs[n * 32 + lk];
        }
#pragma unroll
        for (int mi = 0; mi < MI; mi++)
#pragma unroll
            for (int ni = 0; ni < NI; ni++)
                acc[mi][ni] = __builtin_amdgcn_mfma_f32_16x16x32_bf16(
                    af[mi], bf[ni], acc[mi][ni], 0, 0, 0);
    }

#pragma unroll
    for (int mi = 0; mi < MI; mi++) {
#pragma unroll
        for (int ni = 0; ni < NI; ni++) {
            int col = bx + wx * (NI * 16) + ni * 16 + lr;
#pragma unroll
            for (int r = 0; r < 4; r++) {
                int row = by + wy * (MI * 16) + mi * 16 + (lane >> 4) * 4 + r;
                float v = acc[mi][ni][r];
                if (EPI == 2) {
                    v += bias[col];
                    v = (v > 20.f) ? v : log1pf(__expf(v));
                }
                if (EPI == 1)
                    ((u16*)Cout)[(size_t)row * ldc + col] = f2b(v);
                else
                    ((float*)Cout)[(size_t)row * ldc + col] = v;
            }
        }
    }
}

// ---------------------------------------------------------------------------
// Depthwise causal conv (K=4) + bias + SiLU. bf16 in (xz, stride 4096), bf16 out.
// ---------------------------------------------------------------------------
__global__ __launch_bounds__(256)
void conv_silu(const u16* __restrict__ xzb, const float* __restrict__ cw,
               const float* __restrict__ cb, u16* __restrict__ xpb)
{
    int idx = blockIdx.x * 256 + threadIdx.x;
    int e = idx & (ED_ - 1);
    int l = (idx >> 11) & (L_ - 1);
    int b = idx >> 22;
    const float w0 = cw[e * 4 + 0], w1 = cw[e * 4 + 1];
    const float w2 = cw[e * 4 + 2], w3 = cw[e * 4 + 3];
    const u16* base = xzb + (size_t)(b * L_) * 4096 + e;
    float x0 = (l >= 3) ? b2f(base[(size_t)(l - 3) * 4096]) : 0.f;
    float x1 = (l >= 2) ? b2f(base[(size_t)(l - 2) * 4096]) : 0.f;
    float x2 = (l >= 1) ? b2f(base[(size_t)(l - 1) * 4096]) : 0.f;
    float x3 = b2f(base[(size_t)l * 4096]);
    float v = cb[e] + w0 * x0 + w1 * x1 + w2 * x2 + w3 * x3;
    v = v / (1.f + __expf(-v));
    xpb[idx] = f2b(v);
}

// ---------------------------------------------------------------------------
// Chunked selective scan. A pre-scaled by log2e -> raw v_exp (exp2).
// pass1: per-chunk scan from h=0 -> hbuf (h_out), sumd. Grid (128, NCH-1, G).
// ---------------------------------------------------------------------------
__global__ __launch_bounds__(256)
void scan_pass1(const float* __restrict__ delta, const float* __restrict__ xdbl,
                const u16* __restrict__ xpb, const float* __restrict__ A_log,
                float* __restrict__ hbuf, float* __restrict__ sumd)
{
    const int tid = threadIdx.x;
    const int c = tid >> 4, j = tid & 15;
    const int b = blockIdx.z, ch = blockIdx.y;
    const int e = (blockIdx.x << 4) + c;
    const int l0 = ch * SCH_;

    float4 Al = *(const float4*)(A_log + (size_t)e * 64 + 4 * j);
    const float A0 = -__expf(Al.x) * LOG2E_, A1 = -__expf(Al.y) * LOG2E_;
    const float A2 = -__expf(Al.z) * LOG2E_, A3 = -__expf(Al.w) * LOG2E_;

    float h0 = 0.f, h1 = 0.f, h2 = 0.f, h3 = 0.f, sd = 0.f;
    size_t rowED  = ((size_t)(b * L_) + l0) * ED_ + e;
    size_t row192 = ((size_t)(b * L_) + l0) * 192;

    float  dv = delta[rowED];
    float4 Bv = *(const float4*)(xdbl + row192 + 64 + 4 * j);
    float  xv = b2f(xpb[rowED]);

#pragma unroll 2
    for (int s = 0; s < SCH_ - 1; ++s) {
        float  dn = delta[rowED + ED_];
        float4 Bn = *(const float4*)(xdbl + row192 + 192 + 64 + 4 * j);
        float  xn = b2f(xpb[rowED + ED_]);

        float dx = dv * xv;
        h0 = fexp2(dv * A0) * h0 + dx * Bv.x;
        h1 = fexp2(dv * A1) * h1 + dx * Bv.y;
        h2 = fexp2(dv * A2) * h2 + dx * Bv.z;
        h3 = fexp2(dv * A3) * h3 + dx * Bv.w;
        sd += dv;
        dv = dn; Bv = Bn; xv = xn;
        rowED += ED_; row192 += 192;
    }
    {   // final step, no prefetch
        float dx = dv * xv;
        h0 = fexp2(dv * A0) * h0 + dx * Bv.x;
        h1 = fexp2(dv * A1) * h1 + dx * Bv.y;
        h2 = fexp2(dv * A2) * h2 + dx * Bv.z;
        h3 = fexp2(dv * A3) * h3 + dx * Bv.w;
        sd += dv;
    }
    size_t slot = (((size_t)(b * NCH_ + ch) * ED_) + e) * 64 + 4 * j;
    *(float4*)(hbuf + slot) = make_float4(h0, h1, h2, h3);
    if (j == 0) sumd[(size_t)(b * NCH_ + ch) * ED_ + e] = sd;
}

// ---------------------------------------------------------------------------
// pass2: sequential combine; hbuf[c] rewritten with h_in for chunk c.
// ---------------------------------------------------------------------------
__global__ __launch_bounds__(256)
void scan_pass2(float* __restrict__ hbuf, const float* __restrict__ sumd,
                const float* __restrict__ A_log)
{
    int idx = blockIdx.x * 256 + threadIdx.x;
    int n = idx & 63;
    int e = (idx >> 6) & (ED_ - 1);
    int b = idx >> 17;
    float A = -__expf(A_log[e * 64 + n]) * LOG2E_;
    float h = 0.f;
#pragma unroll
    for (int c = 0; c < NCH_; ++c) {
        size_t slot = (((size_t)(b * NCH_ + c) * ED_) + e) * 64 + n;
        float v = 0.f, sd = 0.f;
        if (c < NCH_ - 1) {
            v  = hbuf[slot];
            sd = sumd[(size_t)(b * NCH_ + c) * ED_ + e];
        }
        hbuf[slot] = h;                   // h_in for chunk c
        if (c < NCH_ - 1) h = fexp2(A * sd) * h + v;
    }
}

// ---------------------------------------------------------------------------
// pass3: re-scan from h_in; C-dot + reduce; y rotated into lane (t&15) via
// cndmask; z-load + SiLU + bf16 store batched once per 16 steps (all 16
// lanes in parallel). y written IN PLACE over xpb. Grid (128, NCH, G).
// ---------------------------------------------------------------------------
__global__ __launch_bounds__(256)
void scan_pass3(const float* __restrict__ delta, const float* __restrict__ xdbl,
                const u16* __restrict__ xzb, u16* __restrict__ xpb,
                const float* __restrict__ A_log, const float* __restrict__ Dp,
                const float* __restrict__ hbuf)
{
    const int tid = threadIdx.x;
    const int c = tid >> 4, j = tid & 15;
    const int b = blockIdx.z, ch = blockIdx.y;
    const int e = (blockIdx.x << 4) + c;
    const int l0 = ch * SCH_;

    float4 Al = *(const float4*)(A_log + (size_t)e * 64 + 4 * j);
    const float A0 = -__expf(Al.x) * LOG2E_, A1 = -__expf(Al.y) * LOG2E_;
    const float A2 = -__expf(Al.z) * LOG2E_, A3 = -__expf(Al.w) * LOG2E_;
    const float dpe = Dp[e];

    size_t slot = (((size_t)(b * NCH_ + ch) * ED_) + e) * 64 + 4 * j;
    float4 hi = *(const float4*)(hbuf + slot);
    float h0 = hi.x, h1 = hi.y, h2 = hi.z, h3 = hi.w;

    size_t rowED  = ((size_t)(b * L_) + l0) * ED_ + e;
    size_t row192 = ((size_t)(b * L_) + l0) * 192;
    const size_t yBase = rowED;
    const size_t zBase = ((size_t)(b * L_) + l0) * 4096 + ED_ + e;

    float  dv = delta[rowED];
    float4 Bv = *(const float4*)(xdbl + row192 + 64 + 4 * j);
    float4 Cv = *(const float4*)(xdbl + row192 + 128 + 4 * j);
    float  xv = b2f(xpb[rowED]);

    float yreg = 0.f;
    for (int kk = 0; kk < SCH_ / 16; ++kk) {
#pragma unroll
        for (int t = 0; t < 16; ++t) {
            float dn = 0.f, xn = 0.f;
            float4 Bn = make_float4(0, 0, 0, 0), Cn = Bn;
            if (t < 15 || kk < SCH_ / 16 - 1) {   // t<15 is compile-time
                dn = delta[rowED + ED_];
                Bn = *(const float4*)(xdbl + row192 + 192 + 64 + 4 * j);
                Cn = *(const float4*)(xdbl + row192 + 192 + 128 + 4 * j);
                xn = b2f(xpb[rowED + ED_]);
            }
            float dx = dv * xv;
            h0 = fexp2(dv * A0) * h0 + dx * Bv.x;
            h1 = fexp2(dv * A1) * h1 + dx * Bv.y;
            h2 = fexp2(dv * A2) * h2 + dx * Bv.z;
            h3 = fexp2(dv * A3) * h3 + dx * Bv.w;

            float acc = h0 * Cv.x + h1 * Cv.y + h2 * Cv.z + h3 * Cv.w;
            acc += __shfl_xor(acc, 1); acc += __shfl_xor(acc, 2);
            acc += __shfl_xor(acc, 4); acc += __shfl_xor(acc, 8);
            float yv = acc + xv * dpe;
            if (j == t) yreg = yv;               // rotate y into lane t

            dv = dn; Bv = Bn; Cv = Cn; xv = xn;
            rowED += ED_; row192 += 192;
        }
        // batched epilogue: lane j owns row l0 + kk*16 + j
        float z = b2f(xzb[zBase + (size_t)(kk * 16 + j) * 4096]);
        float sz = z / (1.f + __expf(-z));
        xpb[yBase + (size_t)(kk * 16 + j) * ED_] = f2b(yreg * sz);
    }
}

// ---------------------------------------------------------------------------
// x = rmsnorm(t, norm_w) + x ; also writes bf16 copy of new x.
// ---------------------------------------------------------------------------
__global__ __launch_bounds__(256)
void rmsnorm_res(const float* __restrict__ t, const float* __restrict__ nw,
                 float* __restrict__ x, u16* __restrict__ xb)
{
    const int row = blockIdx.x;
    const int tid = threadIdx.x;
    const float* tr = t + (size_t)row * D_;
    float* xr = x + (size_t)row * D_;
    u16* xbr = xb + (size_t)row * D_;
    float4 v = *(const float4*)(tr + tid * 4);
    float ss = v.x * v.x + v.y * v.y + v.z * v.z + v.w * v.w;
#pragma unroll
    for (int m = 1; m < 64; m <<= 1) ss += __shfl_xor(ss, m);
    __shared__ float red[4];
    if ((tid & 63) == 0) red[tid >> 6] = ss;
    __syncthreads();
    float tot = red[0] + red[1] + red[2] + red[3];
    float scale = rsqrtf(tot * (1.f / (float)D_) + 1e-5f);
    float4 w = *(const float4*)(nw + tid * 4);
    float4 xo = *(const float4*)(xr + tid * 4);
    xo.x += v.x * scale * w.x;
    xo.y += v.y * scale * w.y;
    xo.z += v.z * scale * w.z;
    xo.w += v.w * scale * w.w;
    *(float4*)(xr + tid * 4) = xo;
    ushort4 hb;
    hb.x = f2b(xo.x); hb.y = f2b(xo.y); hb.z = f2b(xo.z); hb.w = f2b(xo.w);
    *(ushort4*)(xbr + tid * 4) = hb;
}

// ---------------------------------------------------------------------------
__global__ __launch_bounds__(256)
void head_kernel(const float* __restrict__ x, const float* __restrict__ Wh,
                 const float* __restrict__ bh, float* __restrict__ out)
{
    const int b = blockIdx.x >> 1, c = blockIdx.x & 1;
    const int tid = threadIdx.x;
    const float* xr = x + (size_t)(b * L_ + (L_ - 1)) * D_;
    const float* wr = Wh + c * D_;
    float4 xv = *(const float4*)(xr + tid * 4);
    float4 wv = *(const float4*)(wr + tid * 4);
    float s = xv.x * wv.x + xv.y * wv.y + xv.z * wv.z + xv.w * wv.w;
#pragma unroll
    for (int m = 1; m < 64; m <<= 1) s += __shfl_xor(s, m);
    __shared__ float red[4];
    if ((tid & 63) == 0) red[tid >> 6] = s;
    __syncthreads();
    if (tid == 0) out[b * 2 + c] = red[0] + red[1] + red[2] + red[3] + bh[c];
}

// ---------------------------------------------------------------------------
extern "C" void kernel_launch(void* const* d_in, const int* in_sizes, int n_in,
                              void* d_out, int out_size, void* d_ws, size_t ws_size,
                              hipStream_t stream)
{
    const float* x_in   = (const float*)d_in[0];
    const float* W_in   = (const float*)d_in[1];
    const float* conv_w = (const float*)d_in[2];
    const float* conv_b = (const float*)d_in[3];
    const float* W_x    = (const float*)d_in[4];
    const float* W_dt   = (const float*)d_in[5];
    const float* b_dt   = (const float*)d_in[6];
    const float* A_log  = (const float*)d_in[7];
    const float* D_p    = (const float*)d_in[8];
    const float* W_out  = (const float*)d_in[9];
    const float* norm_w = (const float*)d_in[10];
    const float* W_head = (const float*)d_in[11];
    const float* b_head = (const float*)d_in[12];
    float* out = (float*)d_out;

    // -------- bf16 weight region (fixed, head of ws) --------
    const size_t nWi = (size_t)NL_ * 2 * ED_ * D_;
    const size_t nWx = (size_t)NL_ * 192 * ED_;
    const size_t nWo = (size_t)NL_ * D_ * ED_;
    const size_t nWd = (size_t)NL_ * ED_ * 64;
    u16* Wi_b = (u16*)d_ws;
    u16* Wx_b = Wi_b + nWi;
    u16* Wo_b = Wx_b + nWx;
    u16* Wd_b = Wo_b + nWo;
    size_t wbytes = ((nWi + nWx + nWo + nWd) * 2 + 255) & ~(size_t)255;
    char* gb = (char*)d_ws + wbytes;
    size_t usable = ws_size - wbytes;

    cast_bf16<<<(int)(nWi / 256), 256, 0, stream>>>(W_in, Wi_b, (int)nWi);
    cast_bf16<<<(int)(nWx / 256), 256, 0, stream>>>(W_x,  Wx_b, (int)nWx);
    cast_bf16<<<(int)(nWo / 256), 256, 0, stream>>>(W_out, Wo_b, (int)nWo);
    cast_bf16<<<(int)(nWd / 256), 256, 0, stream>>>(W_dt,  Wd_b, (int)nWd);

    // per-batch: activations + hbuf + sumd + dtb
    const size_t perB = (size_t)L_ * (D_ * 4 + 192 * 4 + ED_ * 4 + 4096 * 2 + ED_ * 2)
                      + (size_t)NCH_ * ED_ * 64 * 4 + (size_t)NCH_ * ED_ * 4
                      + (size_t)L_ * 64 * 2;
    int G = 8;
    while (G > 1 && (size_t)G * perB > usable) G >>= 1;
    const int M = G * L_;

    // group-local layout
    float* x_cur = (float*)gb;                       // M*1024 f32
    float* xdbl  = x_cur + (size_t)M * D_;           // M*192  f32
    float* delta = xdbl + (size_t)M * 192;           // M*2048 f32
    u16*   x_b   = (u16*)delta;                      // alias (head of delta)
    u16*   xz_b  = (u16*)(delta + (size_t)M * ED_);  // M*4096 bf16
    u16*   xps_b = xz_b + (size_t)M * 4096;          // M*2048 bf16 (x, then y)
    float* hbuf  = (float*)(xps_b + (size_t)M * ED_);// G*NCH*ED*64 f32
    float* sumd  = hbuf + (size_t)G * NCH_ * ED_ * 64; // G*NCH*ED f32
    u16*   dtb   = (u16*)(sumd + (size_t)G * NCH_ * ED_); // M*64 bf16
    float* out_t = (float*)xz_b;                     // alias (GEMM3 out)

    for (int g0 = 0; g0 < B_; g0 += G) {
        const float* xg = x_in + (size_t)g0 * L_ * D_;
        hipMemcpyAsync(x_cur, xg, (size_t)M * D_ * sizeof(float),
                       hipMemcpyDeviceToDevice, stream);
        cast_bf16<<<(M * D_) / 256, 256, 0, stream>>>(xg, x_b, M * D_);

        for (int i = 0; i < NL_; ++i) {
            // 1) xz = x @ W_in^T  (M x 4096 x 1024), bf16 out
            gemm_mfma<128, 1><<<dim3(4096 / 128, M / 128), 256, 0, stream>>>(
                x_b, D_, Wi_b + (size_t)i * 2 * ED_ * D_, nullptr, xz_b, 4096, D_);
            // 2) xps = silu(conv(xp) + cb), bf16
            conv_silu<<<(M * ED_) / 256, 256, 0, stream>>>(
                xz_b, conv_w + (size_t)i * ED_ * 4, conv_b + (size_t)i * ED_, xps_b);
            // 3) xdbl = xps @ W_x^T  (M x 192 x 2048), fp32 out
            gemm_mfma<64, 0><<<dim3(192 / 64, M / 128), 256, 0, stream>>>(
                xps_b, ED_, Wx_b + (size_t)i * 192 * ED_, nullptr, xdbl, 192, ED_);
            // 4) dtb = bf16(xdbl[:, :64]); delta = softplus(dtb @ W_dt^T + b_dt)
            cast_dt<<<(M * 64) / 256, 256, 0, stream>>>(xdbl, dtb);
            gemm_mfma<128, 2><<<dim3(ED_ / 128, M / 128), 256, 0, stream>>>(
                dtb, 64, Wd_b + (size_t)i * ED_ * 64, b_dt + (size_t)i * ED_,
                delta, ED_, 64);
            // 5) chunked scan
            scan_pass1<<<dim3(128, NCH_ - 1, G), 256, 0, stream>>>(
                delta, xdbl, xps_b, A_log + (size_t)i * ED_ * 64, hbuf, sumd);
            scan_pass2<<<G * 512, 256, 0, stream>>>(
                hbuf, sumd, A_log + (size_t)i * ED_ * 64);
            scan_pass3<<<dim3(128, NCH_, G), 256, 0, stream>>>(
                delta, xdbl, xz_b, xps_b,
                A_log + (size_t)i * ED_ * 64, D_p + (size_t)i * ED_, hbuf);
            // 6) out_t = y @ W_out^T  (M x 1024 x 2048), fp32 out
            gemm_mfma<128, 0><<<dim3(D_ / 128, M / 128), 256, 0, stream>>>(
                xps_b, ED_, Wo_b + (size_t)i * D_ * ED_, nullptr, out_t, D_, ED_);
            // 7) x = rmsnorm(out_t) + x  (+ bf16 copy)
            rmsnorm_res<<<M, 256, 0, stream>>>(out_t, norm_w + (size_t)i * D_,
                                               x_cur, x_b);
        }
        head_kernel<<<G * NC_, 256, 0, stream>>>(x_cur, W_head, b_head,
                                                 out + (size_t)g0 * NC_);
    }
}